// Round 11
// baseline (680.227 us; speedup 1.0000x reference)
//
#include <hip/hip_runtime.h>
#include <hip/hip_bf16.h>

// ---------------- problem constants ----------------
#define N_NODESC 10000
#define M_PAD    10112          // 79 * 128
#define RT_TILES 79
#define NUM_GENE 2000
#define KPAD_G   2048
#define N_EDGESC 160000
#define E_TOT    170000         // + self loops
#define HEADS    10
#define F1       1280           // HEADS*128
#define LATENTC  128
#define LOWERC   64
#define CLUST    15

typedef __attribute__((ext_vector_type(8))) short   short8;
typedef __attribute__((ext_vector_type(4))) float   f32x4;
typedef __attribute__((ext_vector_type(4))) unsigned short ushort4_;

__device__ __forceinline__ float bf2f(unsigned short u){
    unsigned int x = ((unsigned int)u) << 16;
    return __builtin_bit_cast(float, x);
}
__device__ __forceinline__ unsigned short f2bf(float f){
    __hip_bfloat16 h = __float2bfloat16(f);
    return __builtin_bit_cast(unsigned short, h);
}
__device__ __forceinline__ void gload16(const void* g, void* l) {
    __builtin_amdgcn_global_load_lds((const __attribute__((address_space(1))) void*)g,
                                     (__attribute__((address_space(3))) void*)l, 16, 0, 0);
}

// ======== 256x256 bf16 MFMA GEMM — 4-phase quadrant schedule, counted vmcnt ========
// R10 base + deeper stage pipeline: issue A0',B0' at ph0, B1' at ph1, A1' at ph2.
// Waits: ph0 vmcnt(4) [B1,A1 flying], ph1 vmcnt(4) [A0',B0' flying]. 2 barriers/K-tile.
// FOLD=1: last N-tile (bn==NT-1) is the folded MLP1 block: qb==0 cols -> bf16
// relu(val+mbias) into mout[row][col] for slab-0 real rows; no C write for that tile.
template<int OMODE, int FOLD>   // OMODE: 0 bf16 out, 1 f32 out
__global__ __launch_bounds__(512, 2)
void gemm256(const unsigned short* __restrict__ A, int lda,
             const unsigned short* __restrict__ BT, int ldb,
             void* __restrict__ Cp, int ldc,
             int NK, int NT, int M_real,
             const float* __restrict__ mbias, unsigned short* __restrict__ mout)
{
    __shared__ short smem[65536];   // 128 KiB

    const int nwg = gridDim.x;
    const int q = nwg >> 3, r = nwg & 7;
    const int xcd = blockIdx.x & 7, idx = blockIdx.x >> 3;
    const int wgid = (xcd < r ? xcd * (q + 1) : r * (q + 1) + (xcd - r) * q) + idx;
    const int bm = wgid / NT, bn = wgid - bm * NT;

    const int t = threadIdx.x, w = t >> 6, lane = t & 63;
    const int wr2 = (w >> 2) * 64;
    const int wc2 = (w & 3) * 32;
    const int lrow = lane & 15, lq = lane >> 4;

    int rowc[2], swc[2], loff[2];
    #pragma unroll
    for (int cc = 0; cc < 2; ++cc) {
        int c = cc * 512 + t;
        int row = c >> 3, slot = c & 7;
        rowc[cc] = row;
        swc[cc]  = (slot ^ (row & 7)) << 3;
        loff[cc] = c * 8;
    }
    auto stageA = [&](int buf, int h, int kt) {
        short* dst = smem + buf * 32768 + h * 8192;
        const unsigned short* src = A + (size_t)(bm * 256 + h * 128) * lda + kt * 64;
        #pragma unroll
        for (int cc = 0; cc < 2; ++cc)
            gload16(src + (size_t)rowc[cc] * lda + swc[cc], dst + loff[cc]);
    };
    auto stageB = [&](int buf, int h, int kt) {
        short* dst = smem + buf * 32768 + 16384 + h * 8192;
        const unsigned short* src = BT + (size_t)(bn * 256 + h * 128) * ldb + kt * 64;
        #pragma unroll
        for (int cc = 0; cc < 2; ++cc)
            gload16(src + (size_t)rowc[cc] * ldb + swc[cc], dst + loff[cc]);
    };
    auto rdA = [&](int buf, int h, int mi, int ks) -> short8 {
        int r7 = wr2 + mi * 16 + lrow;
        return *(const short8*)(smem + buf * 32768 + h * 8192 + r7 * 64
                                + (((ks * 4 + lq) ^ (r7 & 7)) << 3));
    };
    auto rdB = [&](int buf, int h, int ni, int ks) -> short8 {
        int r7 = wc2 + ni * 16 + lrow;
        return *(const short8*)(smem + buf * 32768 + 16384 + h * 8192 + r7 * 64
                                + (((ks * 4 + lq) ^ (r7 & 7)) << 3));
    };

    f32x4 acc00[4][2] = {}, acc01[4][2] = {}, acc10[4][2] = {}, acc11[4][2] = {};
    short8 a0[4][2], a1[4][2], b0[2][2], b1[2][2];

    auto domfma = [&](f32x4 (&ac)[4][2], short8 (&aa)[4][2], short8 (&bb)[2][2]) {
        __builtin_amdgcn_s_setprio(1);
        #pragma unroll
        for (int mi = 0; mi < 4; ++mi)
            #pragma unroll
            for (int ni = 0; ni < 2; ++ni)
                #pragma unroll
                for (int ks = 0; ks < 2; ++ks)
                    ac[mi][ni] = __builtin_amdgcn_mfma_f32_16x16x32_bf16(
                        aa[mi][ks], bb[ni][ks], ac[mi][ni], 0, 0, 0);
        __builtin_amdgcn_s_setprio(0);
    };

    // prologue: tile 0 in consumption order A0,B0,B1,A1 (8 gloads/thread)
    stageA(0, 0, 0); stageB(0, 0, 0); stageB(0, 1, 0); stageA(0, 1, 0);

    for (int kt = 0; kt < NK; ++kt) {
        const int buf = kt & 1, nbuf = buf ^ 1;
        const bool pf = (kt + 1 < NK);
        // ---- phase 0: quadrant (0,0); needs A0,B0 of tile kt ----
        asm volatile("s_waitcnt vmcnt(4)" ::: "memory");   // A0,B0 landed; B1,A1 flying
        __builtin_amdgcn_sched_barrier(0);
        __builtin_amdgcn_s_barrier();
        __builtin_amdgcn_sched_barrier(0);
        #pragma unroll
        for (int mi = 0; mi < 4; ++mi) { a0[mi][0] = rdA(buf, 0, mi, 0); a0[mi][1] = rdA(buf, 0, mi, 1); }
        #pragma unroll
        for (int ni = 0; ni < 2; ++ni) { b0[ni][0] = rdB(buf, 0, ni, 0); b0[ni][1] = rdB(buf, 0, ni, 1); }
        if (pf) { stageA(nbuf, 0, kt + 1); stageB(nbuf, 0, kt + 1); }
        domfma(acc00, a0, b0);
        // ---- phase 1: merged wait covers B1 AND A1 of tile kt ----
        if (pf) { asm volatile("s_waitcnt vmcnt(4)" ::: "memory"); }  // B1,A1 landed; A0',B0' flying
        else    { asm volatile("s_waitcnt vmcnt(0)" ::: "memory"); }
        __builtin_amdgcn_sched_barrier(0);
        __builtin_amdgcn_s_barrier();
        __builtin_amdgcn_sched_barrier(0);
        #pragma unroll
        for (int ni = 0; ni < 2; ++ni) { b1[ni][0] = rdB(buf, 1, ni, 0); b1[ni][1] = rdB(buf, 1, ni, 1); }
        if (pf) stageB(nbuf, 1, kt + 1);
        domfma(acc01, a0, b1);
        // ---- phase 2: quadrant (1,0); no wait/barrier (A1 synced at ph1) ----
        #pragma unroll
        for (int mi = 0; mi < 4; ++mi) { a1[mi][0] = rdA(buf, 1, mi, 0); a1[mi][1] = rdA(buf, 1, mi, 1); }
        if (pf) stageA(nbuf, 1, kt + 1);
        domfma(acc10, a1, b0);
        // ---- phase 3: quadrant (1,1); registers only ----
        domfma(acc11, a1, b1);
    }

    const bool mlp_tile = FOLD && (bn == NT - 1);
    #pragma unroll
    for (int qa = 0; qa < 2; ++qa) {
        #pragma unroll
        for (int qb = 0; qb < 2; ++qb) {
            f32x4 (&ac)[4][2] = (qa == 0) ? (qb == 0 ? acc00 : acc01)
                                          : (qb == 0 ? acc10 : acc11);
            if (mlp_tile) {
                if (qb != 0) continue;
                #pragma unroll
                for (int mi = 0; mi < 4; ++mi) {
                    #pragma unroll
                    for (int ni = 0; ni < 2; ++ni) {
                        int col = wc2 + ni * 16 + lrow;          // 0..127
                        #pragma unroll
                        for (int qq = 0; qq < 4; ++qq) {
                            int grow = bm * 256 + qa * 128 + wr2 + mi * 16 + lq * 4 + qq;
                            if (grow < N_NODESC) {
                                float val = fmaxf(ac[mi][ni][qq] + mbias[col], 0.f);
                                mout[(size_t)grow * 128 + col] = f2bf(val);
                            }
                        }
                    }
                }
                continue;
            }
            #pragma unroll
            for (int mi = 0; mi < 4; ++mi) {
                #pragma unroll
                for (int ni = 0; ni < 2; ++ni) {
                    int gcol = bn * 256 + qb * 128 + wc2 + ni * 16 + lrow;
                    #pragma unroll
                    for (int qq = 0; qq < 4; ++qq) {
                        int grow = bm * 256 + qa * 128 + wr2 + mi * 16 + lq * 4 + qq;
                        float val = ac[mi][ni][qq];
                        int rslab = grow >= M_PAD ? grow - M_PAD : grow;
                        if (rslab >= M_real) val = 0.f;
                        if constexpr (OMODE == 0)
                            ((unsigned short*)Cp)[(size_t)grow * ldc + gcol] = f2bf(val);
                        else
                            ((float*)Cp)[(size_t)grow * ldc + gcol] = val;
                    }
                }
            }
        }
    }
}

// ---------------- 128x128 bf16 GEMM (MLP2), dbuf 2-phase ----------------
template<int OMODE, int BIAS, int RELU>
__global__ __launch_bounds__(256)
void gemm2(const unsigned short* __restrict__ A, int lda,
           const unsigned short* __restrict__ BT, int ldb,
           const float* __restrict__ bias,
           void* __restrict__ Cp, int ldc,
           int KT, int NT, int M_real)
{
    __shared__ short smem[16384];

    const int nwg = gridDim.x;
    const int q = nwg >> 3, r = nwg & 7;
    const int xcd = blockIdx.x & 7, idx = blockIdx.x >> 3;
    const int wgid = (xcd < r ? xcd * (q + 1) : r * (q + 1) + (xcd - r) * q) + idx;
    const int bm = wgid / NT, bn = wgid - bm * NT;

    const int t = threadIdx.x, w = t >> 6, lane = t & 63;
    const int wr = (w >> 1) * 64, wc = (w & 1) * 64;
    const int lrow = lane & 15, lq = lane >> 4;

    const unsigned short* Ag[2];
    const unsigned short* Bg[2];
    int lds_off[2];
    #pragma unroll
    for (int cc = 0; cc < 2; ++cc) {
        int c = cc * 256 + t;
        int row = c >> 2, slot = c & 3;
        int gk = (slot ^ ((row >> 1) & 3)) << 3;
        Ag[cc] = A  + (size_t)(bm * 128 + row) * lda + gk;
        Bg[cc] = BT + (size_t)(bn * 128 + row) * ldb + gk;
        lds_off[cc] = cc * 2048 + w * 512 + lane * 8;
    }

    auto stage = [&](int buf, int kt) {
        const int kk = kt * 32;
        #pragma unroll
        for (int cc = 0; cc < 2; ++cc) {
            gload16(Ag[cc] + kk, smem + buf * 8192 + lds_off[cc]);
            gload16(Bg[cc] + kk, smem + buf * 8192 + 4096 + lds_off[cc]);
        }
    };

    f32x4 acc[4][4] = {};
    stage(0, 0);
    __syncthreads();
    int cur = 0;
    for (int kt = 0; kt < KT; ++kt) {
        if (kt + 1 < KT) stage(cur ^ 1, kt + 1);
        const short* As = smem + cur * 8192;
        const short* Bs = As + 4096;
        short8 af[4], bf_[4];
        #pragma unroll
        for (int mi = 0; mi < 4; ++mi) {
            int rr = wr + mi * 16 + lrow;
            af[mi] = *(const short8*)(&As[rr * 32 + ((lq ^ ((rr >> 1) & 3)) << 3)]);
        }
        #pragma unroll
        for (int ni = 0; ni < 4; ++ni) {
            int rr = wc + ni * 16 + lrow;
            bf_[ni] = *(const short8*)(&Bs[rr * 32 + ((lq ^ ((rr >> 1) & 3)) << 3)]);
        }
        #pragma unroll
        for (int mi = 0; mi < 4; ++mi)
            #pragma unroll
            for (int ni = 0; ni < 4; ++ni)
                acc[mi][ni] = __builtin_amdgcn_mfma_f32_16x16x32_bf16(af[mi], bf_[ni], acc[mi][ni], 0, 0, 0);
        __syncthreads();
        cur ^= 1;
    }

    #pragma unroll
    for (int mi = 0; mi < 4; ++mi) {
        #pragma unroll
        for (int ni = 0; ni < 4; ++ni) {
            int gcol = bn * 128 + wc + ni * 16 + lrow;
            #pragma unroll
            for (int qq = 0; qq < 4; ++qq) {
                int grow = bm * 128 + wr + mi * 16 + lq * 4 + qq;
                float val = acc[mi][ni][qq];
                if constexpr (BIAS) val += bias[gcol];
                if constexpr (RELU) val = fmaxf(val, 0.f);
                if (grow >= M_real) val = 0.f;
                ((float*)Cp)[(size_t)grow * ldc + gcol] = val;
            }
        }
    }
}

// ---------------- x -> bf16 slab0 AND x_aug -> bf16 slab1 ----------------
__global__ void convert_both_k(const float* __restrict__ x, const float* __restrict__ noise,
                               unsigned short* __restrict__ out)
{
    __shared__ float sred[4];
    __shared__ float srn;
    int row = blockIdx.x, t = threadIdx.x;
    int kc = t * 8;
    f32x4 n0 = {}, n1 = {};
    float ss = 0.f;
    if (t < 250) {
        n0 = *(const f32x4*)(noise + (size_t)row * NUM_GENE + kc);
        n1 = *(const f32x4*)(noise + (size_t)row * NUM_GENE + kc + 4);
        ss = n0.x*n0.x + n0.y*n0.y + n0.z*n0.z + n0.w*n0.w
           + n1.x*n1.x + n1.y*n1.y + n1.z*n1.z + n1.w*n1.w;
    }
    for (int off = 32; off; off >>= 1) ss += __shfl_down(ss, off);
    if ((t & 63) == 0) sred[t >> 6] = ss;
    __syncthreads();
    if (t == 0) srn = 1.f / fmaxf(sqrtf(sred[0] + sred[1] + sred[2] + sred[3]), 1e-12f);
    __syncthreads();
    if (t >= 250) return;
    float rn = srn;
    f32x4 a0 = *(const f32x4*)(x + (size_t)row * NUM_GENE + kc);
    f32x4 a1 = *(const f32x4*)(x + (size_t)row * NUM_GENE + kc + 4);
    short8 v0, v1;
    #pragma unroll
    for (int i = 0; i < 4; ++i) {
        v0[i]     = (short)f2bf(a0[i]);
        v0[4 + i] = (short)f2bf(a1[i]);
        v1[i]     = (short)f2bf(a0[i] + n0[i] * rn);
        v1[4 + i] = (short)f2bf(a1[i] + n1[i] * rn);
    }
    *(short8*)(out + (size_t)row * KPAD_G + kc) = v0;
    *(short8*)(out + (size_t)(M_PAD + row) * KPAD_G + kc) = v1;
}

// ---------------- transpose + fp32->bf16 (+K pad zeroed) ----------------
__global__ void transpose_bf_k(const float* __restrict__ in, unsigned short* __restrict__ out,
                               int R, int C, int Kpad)
{
    __shared__ float tile[32][33];
    int tx = threadIdx.x & 31, ty = threadIdx.x >> 5;
    int c0 = blockIdx.x * 32, r0 = blockIdx.y * 32;
    #pragma unroll
    for (int i = 0; i < 4; ++i) {
        int r = r0 + ty + i * 8, c = c0 + tx;
        tile[ty + i * 8][tx] = (r < R && c < C) ? in[(size_t)r * C + c] : 0.f;
    }
    __syncthreads();
    #pragma unroll
    for (int i = 0; i < 4; ++i) {
        int c = c0 + ty + i * 8;
        int r = r0 + tx;
        if (c < C && r < Kpad) out[(size_t)c * Kpad + r] = f2bf(tile[tx][ty + i * 8]);
    }
}

// ---------------- CSR build by dst ----------------
__global__ void hist_k(const int* __restrict__ ei, int* __restrict__ cnt)
{
    int e = blockIdx.x * 256 + threadIdx.x;
    if (e >= E_TOT) return;
    int d = (e < N_EDGESC) ? ei[N_EDGESC + e] : (e - N_EDGESC);
    atomicAdd(&cnt[d], 1);
}

__global__ void scan_k(const int* __restrict__ cnt, int* __restrict__ rowp, int* __restrict__ cursor)
{
    __shared__ int buf[1024];
    int t = threadIdx.x;
    int loc[10];
    int s = 0, base = t * 10;
    #pragma unroll
    for (int i = 0; i < 10; ++i) {
        int idx = base + i;
        int v = (idx < N_NODESC) ? cnt[idx] : 0;
        loc[i] = v; s += v;
    }
    buf[t] = s; __syncthreads();
    for (int off = 1; off < 1024; off <<= 1) {
        int tmp = (t >= off) ? buf[t - off] : 0;
        __syncthreads();
        buf[t] += tmp;
        __syncthreads();
    }
    int run = buf[t] - s;
    #pragma unroll
    for (int i = 0; i < 10; ++i) {
        int idx = base + i;
        if (idx < N_NODESC) { rowp[idx] = run; cursor[idx] = run; run += loc[i]; }
    }
    if (t == 1023) rowp[N_NODESC] = buf[1023];
}

__global__ void scatter_k(const int* __restrict__ ei, int* __restrict__ cursor,
                          int* __restrict__ col_src, int* __restrict__ dst_of)
{
    int e = blockIdx.x * 256 + threadIdx.x;
    if (e >= E_TOT) return;
    int s, d;
    if (e < N_EDGESC) { s = ei[e]; d = ei[N_EDGESC + e]; } else { s = d = e - N_EDGESC; }
    int pos = atomicAdd(&cursor[d], 1);
    col_src[pos] = s;
    dst_of[pos] = d;
}

// ---------------- attention scores for both passes; 320 thr = 2 nodes ----------------
__global__ void escores2_k(const unsigned short* __restrict__ h,
                           const float* __restrict__ a_src, const float* __restrict__ a_dst,
                           float* __restrict__ e_s, float* __restrict__ e_d)
{
    int t = threadIdx.x;
    int half = (t >= 160);
    int tl = t - half * 160;
    int node2 = blockIdx.x * 2 + half;
    int p = node2 >= N_NODESC;
    int n = node2 - p * N_NODESC;
    int hh = tl >> 4, c = tl & 15;
    int off = hh * 128 + c * 8;
    short8 v = *(const short8*)(h + (size_t)(p * M_PAD + n) * F1 + off);
    float ps = 0.f, pd = 0.f;
    #pragma unroll
    for (int j = 0; j < 8; ++j) {
        float f = bf2f((unsigned short)v[j]);
        ps += f * a_src[off + j];
        pd += f * a_dst[off + j];
    }
    #pragma unroll
    for (int m = 1; m < 16; m <<= 1) {
        ps += __shfl_xor(ps, m, 16);
        pd += __shfl_xor(pd, m, 16);
    }
    if (c == 0) { e_s[node2 * HEADS + hh] = ps; e_d[node2 * HEADS + hh] = pd; }
}

// ---------------- per-edge alpha -> TRANSPOSED layout [pass][head][E] ----------------
__global__ void alpha_k(const int* __restrict__ colsrc, const int* __restrict__ dstof,
                        const float* __restrict__ e_s, const float* __restrict__ e_d,
                        float* __restrict__ alpha)
{
    int gid = blockIdx.x * 256 + threadIdx.x;
    if (gid >= 2 * E_TOT) return;
    int p = gid >= E_TOT;
    int e = gid - p * E_TOT;
    int s = colsrc[e], d = dstof[e];
    const float* er = e_s + (size_t)(p * N_NODESC + s) * HEADS;
    const float* dr = e_d + (size_t)(p * N_NODESC + d) * HEADS;
    #pragma unroll
    for (int h = 0; h < HEADS; ++h) {
        float a = er[h] + dr[h];
        a = a >= 0.f ? a : 0.2f * a;
        alpha[((size_t)p * HEADS + h) * E_TOT + e] = a;
    }
}

// ---------------- fused per-(pass,head,node) softmax: max/sum + normalize in-place ----
// consecutive lanes take consecutive nodes of the same (pass,head) plane -> the wave's
// second-pass writes cover a contiguous stretch of alpha; replaces nodems+wexp+minv.
__global__ void nodesm_k(const int* __restrict__ rowp, float* __restrict__ alpha)
{
    int gid = blockIdx.x * 256 + threadIdx.x;
    if (gid >= 2 * N_NODESC * HEADS) return;
    int p = gid >= N_NODESC * HEADS;
    int rr = gid - p * N_NODESC * HEADS;
    int hh = rr / N_NODESC, n = rr - hh * N_NODESC;
    int beg = rowp[n], end = rowp[n + 1];
    float* ap = alpha + ((size_t)p * HEADS + hh) * E_TOT;
    float m = -1e30f, ssum = 0.f;
    for (int e = beg; e < end; ++e) {
        float a = ap[e];
        if (a > m) { ssum = ssum * __expf(m - a) + 1.f; m = a; }
        else ssum += __expf(a - m);
    }
    float inv = 1.f / ssum;
    for (int e = beg; e < end; ++e)
        ap[e] = __expf(ap[e] - m) * inv;
}

// ---------------- sliced aggregation, XCD-chunked ----------------
template<int L1MODE>
__global__ void agg_slice_k(const int* __restrict__ rowp, const int* __restrict__ colsrc,
                            const float* __restrict__ alpha,
                            const unsigned short* __restrict__ h,
                            const float* __restrict__ bias,
                            unsigned short* __restrict__ out)
{
    const int nwg = gridDim.x;             // 12500
    const int q = nwg >> 3, r = nwg & 7;
    const int xcd = blockIdx.x & 7, idx = blockIdx.x >> 3;
    const int wgid = (xcd < r ? xcd * (q + 1) : r * (q + 1) + (xcd - r) * q) + idx;
    int ps = wgid / 625, nb = wgid - ps * 625;
    int p = ps / HEADS, s = ps - p * HEADS;
    int t = threadIdx.x;
    int nl = t >> 4, l16 = t & 15;
    int n = nb * 16 + nl;
    int beg = rowp[n], end = rowp[n + 1];
    const unsigned short* hb = h + (size_t)p * M_PAD * F1 + s * 128 + l16 * 8;
    const float* wb = alpha + ((size_t)p * HEADS + s) * E_TOT;
    float acc[8] = {};
    for (int e = beg; e < end; ++e) {
        int src = colsrc[e];
        float wv = wb[e];
        short8 rv = *(const short8*)(hb + (size_t)src * F1);
        #pragma unroll
        for (int j = 0; j < 8; ++j) acc[j] += wv * bf2f((unsigned short)rv[j]);
    }
    short8 o;
    if constexpr (L1MODE) {
        #pragma unroll
        for (int j = 0; j < 8; ++j)
            o[j] = (short)f2bf(fmaxf(acc[j] + bias[s * 128 + l16 * 8 + j], 0.f));
    } else {
        #pragma unroll
        for (int j = 0; j < 8; ++j) o[j] = (short)f2bf(acc[j]);
    }
    *(short8*)(out + (size_t)(p * M_PAD + n) * F1 + s * 128 + l16 * 8) = o;
}

// ---------------- head-mean + bias + relu ----------------
__global__ void headmean_k(const unsigned short* __restrict__ tmp, const float* __restrict__ b2,
                           float* __restrict__ out)
{
    int gid = blockIdx.x * 256 + threadIdx.x;
    int pn = gid >> 4, d8 = (gid & 15) * 8;
    int p = pn >= N_NODESC;
    int n = pn - p * N_NODESC;
    const unsigned short* tp = tmp + (size_t)(p * M_PAD + n) * F1 + d8;
    float acc[8] = {};
    #pragma unroll
    for (int hh = 0; hh < HEADS; ++hh) {
        short8 v = *(const short8*)(tp + hh * 128);
        #pragma unroll
        for (int j = 0; j < 8; ++j) acc[j] += bf2f((unsigned short)v[j]);
    }
    float* op = out + (size_t)(p * M_PAD + n) * LATENTC + d8;
    #pragma unroll
    for (int j = 0; j < 8; ++j) op[j] = fmaxf(acc[j] * 0.1f + b2[d8 + j], 0.f);
}

// ---------------- column sums for pooling ----------------
__global__ void colsum_k(const float* __restrict__ g01, const float* __restrict__ g2,
                         float* __restrict__ gsum)
{
    int v = blockIdx.x / 40, b = blockIdx.x % 40;
    const float* src = (v == 0) ? g01 : (v == 1) ? g01 + (size_t)M_PAD * 128 : g2;
    int t = threadIdx.x, col = t & 127, ro = t >> 7;
    int rend = min((b + 1) * 250, N_NODESC);
    float acc = 0.f;
    for (int r = b * 250 + ro; r < rend; r += 2) acc += src[(size_t)r * 128 + col];
    __shared__ float part[256];
    part[t] = acc; __syncthreads();
    if (t < 128) atomicAdd(&gsum[v * 128 + col], part[t] + part[t + 128]);
}

// ---------------- contrastive loss scalar ----------------
__global__ void loss_k(const float* __restrict__ gsum, float* __restrict__ out)
{
    int t = threadIdx.x;   // 128
    float g0 = gsum[t] * 1e-4f, g1 = gsum[128 + t] * 1e-4f, g2 = gsum[256 + t] * 1e-4f;
    float d01 = g0 * g1, d02 = g0 * g2, d12 = g1 * g2;
    for (int off = 32; off; off >>= 1) {
        d01 += __shfl_down(d01, off); d02 += __shfl_down(d02, off); d12 += __shfl_down(d12, off);
    }
    __shared__ float s[3][2];
    if ((t & 63) == 0) { int w = t >> 6; s[0][w] = d01; s[1][w] = d02; s[2][w] = d12; }
    __syncthreads();
    if (t == 0) {
        float a01 = (s[0][0] + s[0][1]) * 5.f;
        float a02 = (s[1][0] + s[1][1]) * 5.f;
        float a12 = (s[2][0] + s[2][1]) * 5.f;
        float m = fmaxf(a01, fmaxf(a02, a12));
        float se = expf(a01 - m) + expf(a02 - m) + expf(a12 - m);
        *out = -((a01 - m) - logf(se)) / 2.302585092994046f;
    }
}

// ---------------- projection heads ----------------
__global__ void proj_k(const float* __restrict__ g01, const float* __restrict__ g2,
                       const float* __restrict__ Wf, const float* __restrict__ bfv,
                       const float* __restrict__ Wc, const float* __restrict__ bc,
                       float* __restrict__ out)
{
    __shared__ float rowb[4][128];
    int m = blockIdx.y;
    const float* gx = (m == 0) ? g01 : (m == 1) ? g01 + (size_t)M_PAD * 128 : g2;
    float* out_node = out + (size_t)m * 640000;
    float* out_c = (m == 0) ? out + 1920001 : (m == 1) ? out + 2070001 : nullptr;
    int wid = threadIdx.x >> 6, l = threadIdx.x & 63;
    int n = blockIdx.x * 4 + wid;
    if (n >= N_NODESC) return;
    rowb[wid][l]      = gx[(size_t)n * 128 + l];
    rowb[wid][l + 64] = gx[(size_t)n * 128 + 64 + l];
    float acc = bfv[l];
    #pragma unroll 8
    for (int k = 0; k < 128; ++k) acc += rowb[wid][k] * Wf[k * 64 + l];
    out_node[(size_t)n * 64 + l] = acc;
    if (out_c != nullptr && l < CLUST) {
        float a2 = bc[l];
        #pragma unroll 8
        for (int k = 0; k < 128; ++k) a2 += rowb[wid][k] * Wc[k * CLUST + l];
        out_c[(size_t)l * N_NODESC + n] = a2;
    }
}

// ---------------- host ----------------
extern "C" void kernel_launch(void* const* d_in, const int* in_sizes, int n_in,
                              void* d_out, int out_size, void* d_ws, size_t ws_size,
                              hipStream_t stream)
{
    const float* x     = (const float*)d_in[0];
    const int*   ei    = (const int*)  d_in[1];
    const float* noise = (const float*)d_in[2];
    const float* W1    = (const float*)d_in[3];
    const float* a1s   = (const float*)d_in[4];
    const float* a1d   = (const float*)d_in[5];
    const float* b1    = (const float*)d_in[6];
    const float* W2    = (const float*)d_in[7];
    const float* a2s   = (const float*)d_in[8];
    const float* a2d   = (const float*)d_in[9];
    const float* b2    = (const float*)d_in[10];
    const float* Wm1   = (const float*)d_in[11];
    const float* bm1   = (const float*)d_in[12];
    const float* Wm2   = (const float*)d_in[13];
    const float* bm2   = (const float*)d_in[14];
    const float* Wf    = (const float*)d_in[15];
    const float* bfv   = (const float*)d_in[16];
    const float* Wc    = (const float*)d_in[17];
    const float* bc    = (const float*)d_in[18];
    float* out = (float*)d_out;

    size_t off = 0;
    auto alloc = [&](size_t bytes) { size_t o = off; off = (off + bytes + 255) & ~(size_t)255; return o; };
    char* ws = (char*)d_ws;
    unsigned short* xbuf2  = (unsigned short*)(ws + alloc((size_t)2 * M_PAD * KPAD_G * 2)); // later h1x2 / agg2 tmp
    unsigned short* hraw2  = (unsigned short*)(ws + alloc((size_t)2 * M_PAD * F1 * 2));
    unsigned short* w1t    = (unsigned short*)(ws + alloc((size_t)1536 * KPAD_G * 2));      // W1^T ++ Wm1^T ++ zeros
    unsigned short* w2t    = (unsigned short*)(ws + alloc((size_t)F1 * F1 * 2));
    unsigned short* wm2t   = (unsigned short*)(ws + alloc((size_t)128 * 128 * 2));
    unsigned short* t_bf   = (unsigned short*)(ws + alloc((size_t)M_PAD * 128 * 2));
    float*  alpha  = (float*) (ws + alloc((size_t)2 * E_TOT * HEADS * 4));
    float*  es     = (float*) (ws + alloc((size_t)2 * N_NODESC * HEADS * 4));
    float*  edv    = (float*) (ws + alloc((size_t)2 * N_NODESC * HEADS * 4));
    int*    cnt    = (int*)   (ws + alloc((size_t)N_NODESC * 4));
    int*    rowp   = (int*)   (ws + alloc((size_t)(N_NODESC + 16) * 4));
    int*    cursor = (int*)   (ws + alloc((size_t)N_NODESC * 4));
    int*    colsrc = (int*)   (ws + alloc((size_t)E_TOT * 4));
    int*    dstof  = (int*)   (ws + alloc((size_t)E_TOT * 4));
    float*  gx01   = (float*) (ws + alloc((size_t)2 * M_PAD * 128 * 4));
    float*  gx2    = (float*) (ws + alloc((size_t)M_PAD * 128 * 4));
    float*  gsum   = (float*) (ws + alloc((size_t)384 * 4));
    unsigned short* h1x2 = xbuf2;        // alias: xbuf2 dead after L1 GEMM
    unsigned short* tmp2 = xbuf2;        // alias: h1x2 dead after L2 GEMM
    (void)ws_size; (void)in_sizes; (void)n_in; (void)out_size;

    hipMemsetAsync(cnt, 0, (size_t)N_NODESC * 4, stream);
    hipMemsetAsync(gsum, 0, 384 * 4, stream);
    hipMemsetAsync(w1t + (size_t)1408 * KPAD_G, 0, (size_t)128 * KPAD_G * 2, stream);  // zero-pad B rows

    convert_both_k<<<N_NODESC, 256, 0, stream>>>(x, noise, xbuf2);

    transpose_bf_k<<<dim3(40, 64), 256, 0, stream>>>(W1,  w1t,  NUM_GENE, F1,  KPAD_G);
    transpose_bf_k<<<dim3(4, 64),  256, 0, stream>>>(Wm1, w1t + (size_t)1280 * KPAD_G, NUM_GENE, 128, KPAD_G);
    transpose_bf_k<<<dim3(40, 40), 256, 0, stream>>>(W2,  w2t,  F1,       F1,  F1);
    transpose_bf_k<<<dim3(4, 4),   256, 0, stream>>>(Wm2, wm2t, 128,      128, 128);

    hist_k   <<<(E_TOT + 255) / 256, 256, 0, stream>>>(ei, cnt);
    scan_k   <<<1, 1024, 0, stream>>>(cnt, rowp, cursor);
    scatter_k<<<(E_TOT + 255) / 256, 256, 0, stream>>>(ei, cursor, colsrc, dstof);

    // ---- L1 GEMM with folded MLP layer 1 (N = 1536 = 6 tiles) ----
    gemm256<0,1><<<RT_TILES * 6, 512, 0, stream>>>(xbuf2, KPAD_G, w1t, KPAD_G,
        hraw2, F1, 32, 6, N_NODESC, bm1, t_bf);
    // MLP layer 2 (reads t_bf produced above)
    gemm2<1,1,0><<<RT_TILES, 256, 0, stream>>>(t_bf, 128, wm2t, 128,
        bm2, gx2, 128, 4, 1, N_NODESC);

    escores2_k<<<N_NODESC, 320, 0, stream>>>(hraw2, a1s, a1d, es, edv);
    alpha_k <<<(2 * E_TOT + 255) / 256, 256, 0, stream>>>(colsrc, dstof, es, edv, alpha);
    nodesm_k<<<(2 * N_NODESC * HEADS + 255) / 256, 256, 0, stream>>>(rowp, alpha);
    agg_slice_k<1><<<12500, 256, 0, stream>>>(rowp, colsrc, alpha, hraw2, b1, h1x2);

    gemm256<0,0><<<RT_TILES * 5, 512, 0, stream>>>(h1x2, F1, w2t, F1,
        hraw2, F1, 20, 5, N_NODESC, nullptr, nullptr);
    escores2_k<<<N_NODESC, 320, 0, stream>>>(hraw2, a2s, a2d, es, edv);
    alpha_k <<<(2 * E_TOT + 255) / 256, 256, 0, stream>>>(colsrc, dstof, es, edv, alpha);
    nodesm_k<<<(2 * N_NODESC * HEADS + 255) / 256, 256, 0, stream>>>(rowp, alpha);
    agg_slice_k<0><<<12500, 256, 0, stream>>>(rowp, colsrc, alpha, hraw2, nullptr, tmp2);
    headmean_k<<<1250, 256, 0, stream>>>(tmp2, b2, gx01);

    colsum_k<<<120, 256, 0, stream>>>(gx01, gx2, gsum);
    loss_k  <<<1, 128, 0, stream>>>(gsum, out + 1920000);

    proj_k<<<dim3(2500, 3), 256, 0, stream>>>(gx01, gx2, Wf, bfv, Wc, bc, out);
}

// Round 12
// 654.853 us; speedup vs baseline: 1.0387x; 1.0387x over previous
//
#include <hip/hip_runtime.h>
#include <hip/hip_bf16.h>

// ---------------- problem constants ----------------
#define N_NODESC 10000
#define M_PAD    10112          // 79 * 128
#define RT_TILES 79
#define NUM_GENE 2000
#define KPAD_G   2048
#define N_EDGESC 160000
#define E_TOT    170000         // + self loops
#define HEADS    10
#define F1       1280           // HEADS*128
#define LATENTC  128
#define LOWERC   64
#define CLUST    15

typedef __attribute__((ext_vector_type(8))) short   short8;
typedef __attribute__((ext_vector_type(4))) float   f32x4;
typedef __attribute__((ext_vector_type(4))) unsigned short ushort4_;

__device__ __forceinline__ float bf2f(unsigned short u){
    unsigned int x = ((unsigned int)u) << 16;
    return __builtin_bit_cast(float, x);
}
__device__ __forceinline__ unsigned short f2bf(float f){
    __hip_bfloat16 h = __float2bfloat16(f);
    return __builtin_bit_cast(unsigned short, h);
}
__device__ __forceinline__ void gload16(const void* g, void* l) {
    __builtin_amdgcn_global_load_lds((const __attribute__((address_space(1))) void*)g,
                                     (__attribute__((address_space(3))) void*)l, 16, 0, 0);
}

// ======== 256x256 bf16 MFMA GEMM — 4-phase quadrant schedule, counted vmcnt ========
// R11 schedule (kept): issue A0',B0' at ph0, B1' at ph1, A1' at ph2; waits vmcnt(4)
// at ph0 and ph1; 2 barriers/K-tile; phases 2-3 barrier-free.
// FOLD=1: last N-tile (bn==NT-1) is the folded MLP1 block: qb==0 cols -> bf16
// relu(val+mbias) into mout[row][col] for slab-0 real rows; no C write for that tile.
template<int OMODE, int FOLD>   // OMODE: 0 bf16 out, 1 f32 out
__global__ __launch_bounds__(512, 2)
void gemm256(const unsigned short* __restrict__ A, int lda,
             const unsigned short* __restrict__ BT, int ldb,
             void* __restrict__ Cp, int ldc,
             int NK, int NT, int M_real,
             const float* __restrict__ mbias, unsigned short* __restrict__ mout)
{
    __shared__ short smem[65536];   // 128 KiB

    const int nwg = gridDim.x;
    const int q = nwg >> 3, r = nwg & 7;
    const int xcd = blockIdx.x & 7, idx = blockIdx.x >> 3;
    const int wgid = (xcd < r ? xcd * (q + 1) : r * (q + 1) + (xcd - r) * q) + idx;
    const int bm = wgid / NT, bn = wgid - bm * NT;

    const int t = threadIdx.x, w = t >> 6, lane = t & 63;
    const int wr2 = (w >> 2) * 64;
    const int wc2 = (w & 3) * 32;
    const int lrow = lane & 15, lq = lane >> 4;

    int rowc[2], swc[2], loff[2];
    #pragma unroll
    for (int cc = 0; cc < 2; ++cc) {
        int c = cc * 512 + t;
        int row = c >> 3, slot = c & 7;
        rowc[cc] = row;
        swc[cc]  = (slot ^ (row & 7)) << 3;
        loff[cc] = c * 8;
    }
    auto stageA = [&](int buf, int h, int kt) {
        short* dst = smem + buf * 32768 + h * 8192;
        const unsigned short* src = A + (size_t)(bm * 256 + h * 128) * lda + kt * 64;
        #pragma unroll
        for (int cc = 0; cc < 2; ++cc)
            gload16(src + (size_t)rowc[cc] * lda + swc[cc], dst + loff[cc]);
    };
    auto stageB = [&](int buf, int h, int kt) {
        short* dst = smem + buf * 32768 + 16384 + h * 8192;
        const unsigned short* src = BT + (size_t)(bn * 256 + h * 128) * ldb + kt * 64;
        #pragma unroll
        for (int cc = 0; cc < 2; ++cc)
            gload16(src + (size_t)rowc[cc] * ldb + swc[cc], dst + loff[cc]);
    };
    auto rdA = [&](int buf, int h, int mi, int ks) -> short8 {
        int r7 = wr2 + mi * 16 + lrow;
        return *(const short8*)(smem + buf * 32768 + h * 8192 + r7 * 64
                                + (((ks * 4 + lq) ^ (r7 & 7)) << 3));
    };
    auto rdB = [&](int buf, int h, int ni, int ks) -> short8 {
        int r7 = wc2 + ni * 16 + lrow;
        return *(const short8*)(smem + buf * 32768 + 16384 + h * 8192 + r7 * 64
                                + (((ks * 4 + lq) ^ (r7 & 7)) << 3));
    };

    f32x4 acc00[4][2] = {}, acc01[4][2] = {}, acc10[4][2] = {}, acc11[4][2] = {};
    short8 a0[4][2], a1[4][2], b0[2][2], b1[2][2];

    auto domfma = [&](f32x4 (&ac)[4][2], short8 (&aa)[4][2], short8 (&bb)[2][2]) {
        __builtin_amdgcn_s_setprio(1);
        #pragma unroll
        for (int mi = 0; mi < 4; ++mi)
            #pragma unroll
            for (int ni = 0; ni < 2; ++ni)
                #pragma unroll
                for (int ks = 0; ks < 2; ++ks)
                    ac[mi][ni] = __builtin_amdgcn_mfma_f32_16x16x32_bf16(
                        aa[mi][ks], bb[ni][ks], ac[mi][ni], 0, 0, 0);
        __builtin_amdgcn_s_setprio(0);
    };

    // prologue: tile 0 in consumption order A0,B0,B1,A1 (8 gloads/thread)
    stageA(0, 0, 0); stageB(0, 0, 0); stageB(0, 1, 0); stageA(0, 1, 0);

    for (int kt = 0; kt < NK; ++kt) {
        const int buf = kt & 1, nbuf = buf ^ 1;
        const bool pf = (kt + 1 < NK);
        // ---- phase 0: quadrant (0,0); needs A0,B0 of tile kt ----
        asm volatile("s_waitcnt vmcnt(4)" ::: "memory");   // A0,B0 landed; B1,A1 flying
        __builtin_amdgcn_sched_barrier(0);
        __builtin_amdgcn_s_barrier();
        __builtin_amdgcn_sched_barrier(0);
        #pragma unroll
        for (int mi = 0; mi < 4; ++mi) { a0[mi][0] = rdA(buf, 0, mi, 0); a0[mi][1] = rdA(buf, 0, mi, 1); }
        #pragma unroll
        for (int ni = 0; ni < 2; ++ni) { b0[ni][0] = rdB(buf, 0, ni, 0); b0[ni][1] = rdB(buf, 0, ni, 1); }
        if (pf) { stageA(nbuf, 0, kt + 1); stageB(nbuf, 0, kt + 1); }
        domfma(acc00, a0, b0);
        // ---- phase 1: merged wait covers B1 AND A1 of tile kt ----
        if (pf) { asm volatile("s_waitcnt vmcnt(4)" ::: "memory"); }  // B1,A1 landed; A0',B0' flying
        else    { asm volatile("s_waitcnt vmcnt(0)" ::: "memory"); }
        __builtin_amdgcn_sched_barrier(0);
        __builtin_amdgcn_s_barrier();
        __builtin_amdgcn_sched_barrier(0);
        #pragma unroll
        for (int ni = 0; ni < 2; ++ni) { b1[ni][0] = rdB(buf, 1, ni, 0); b1[ni][1] = rdB(buf, 1, ni, 1); }
        if (pf) stageB(nbuf, 1, kt + 1);
        domfma(acc01, a0, b1);
        // ---- phase 2: quadrant (1,0); no wait/barrier (A1 synced at ph1) ----
        #pragma unroll
        for (int mi = 0; mi < 4; ++mi) { a1[mi][0] = rdA(buf, 1, mi, 0); a1[mi][1] = rdA(buf, 1, mi, 1); }
        if (pf) stageA(nbuf, 1, kt + 1);
        domfma(acc10, a1, b0);
        // ---- phase 3: quadrant (1,1); registers only ----
        domfma(acc11, a1, b1);
    }

    const bool mlp_tile = FOLD && (bn == NT - 1);
    #pragma unroll
    for (int qa = 0; qa < 2; ++qa) {
        #pragma unroll
        for (int qb = 0; qb < 2; ++qb) {
            f32x4 (&ac)[4][2] = (qa == 0) ? (qb == 0 ? acc00 : acc01)
                                          : (qb == 0 ? acc10 : acc11);
            if (mlp_tile) {
                if (qb != 0) continue;
                #pragma unroll
                for (int mi = 0; mi < 4; ++mi) {
                    #pragma unroll
                    for (int ni = 0; ni < 2; ++ni) {
                        int col = wc2 + ni * 16 + lrow;          // 0..127
                        #pragma unroll
                        for (int qq = 0; qq < 4; ++qq) {
                            int grow = bm * 256 + qa * 128 + wr2 + mi * 16 + lq * 4 + qq;
                            if (grow < N_NODESC) {
                                float val = fmaxf(ac[mi][ni][qq] + mbias[col], 0.f);
                                mout[(size_t)grow * 128 + col] = f2bf(val);
                            }
                        }
                    }
                }
                continue;
            }
            #pragma unroll
            for (int mi = 0; mi < 4; ++mi) {
                #pragma unroll
                for (int ni = 0; ni < 2; ++ni) {
                    int gcol = bn * 256 + qb * 128 + wc2 + ni * 16 + lrow;
                    #pragma unroll
                    for (int qq = 0; qq < 4; ++qq) {
                        int grow = bm * 256 + qa * 128 + wr2 + mi * 16 + lq * 4 + qq;
                        float val = ac[mi][ni][qq];
                        int rslab = grow >= M_PAD ? grow - M_PAD : grow;
                        if (rslab >= M_real) val = 0.f;
                        if constexpr (OMODE == 0)
                            ((unsigned short*)Cp)[(size_t)grow * ldc + gcol] = f2bf(val);
                        else
                            ((float*)Cp)[(size_t)grow * ldc + gcol] = val;
                    }
                }
            }
        }
    }
}

// ---------------- 128x128 bf16 GEMM (MLP2), dbuf 2-phase ----------------
template<int OMODE, int BIAS, int RELU>
__global__ __launch_bounds__(256)
void gemm2(const unsigned short* __restrict__ A, int lda,
           const unsigned short* __restrict__ BT, int ldb,
           const float* __restrict__ bias,
           void* __restrict__ Cp, int ldc,
           int KT, int NT, int M_real)
{
    __shared__ short smem[16384];

    const int nwg = gridDim.x;
    const int q = nwg >> 3, r = nwg & 7;
    const int xcd = blockIdx.x & 7, idx = blockIdx.x >> 3;
    const int wgid = (xcd < r ? xcd * (q + 1) : r * (q + 1) + (xcd - r) * q) + idx;
    const int bm = wgid / NT, bn = wgid - bm * NT;

    const int t = threadIdx.x, w = t >> 6, lane = t & 63;
    const int wr = (w >> 1) * 64, wc = (w & 1) * 64;
    const int lrow = lane & 15, lq = lane >> 4;

    const unsigned short* Ag[2];
    const unsigned short* Bg[2];
    int lds_off[2];
    #pragma unroll
    for (int cc = 0; cc < 2; ++cc) {
        int c = cc * 256 + t;
        int row = c >> 2, slot = c & 3;
        int gk = (slot ^ ((row >> 1) & 3)) << 3;
        Ag[cc] = A  + (size_t)(bm * 128 + row) * lda + gk;
        Bg[cc] = BT + (size_t)(bn * 128 + row) * ldb + gk;
        lds_off[cc] = cc * 2048 + w * 512 + lane * 8;
    }

    auto stage = [&](int buf, int kt) {
        const int kk = kt * 32;
        #pragma unroll
        for (int cc = 0; cc < 2; ++cc) {
            gload16(Ag[cc] + kk, smem + buf * 8192 + lds_off[cc]);
            gload16(Bg[cc] + kk, smem + buf * 8192 + 4096 + lds_off[cc]);
        }
    };

    f32x4 acc[4][4] = {};
    stage(0, 0);
    __syncthreads();
    int cur = 0;
    for (int kt = 0; kt < KT; ++kt) {
        if (kt + 1 < KT) stage(cur ^ 1, kt + 1);
        const short* As = smem + cur * 8192;
        const short* Bs = As + 4096;
        short8 af[4], bf_[4];
        #pragma unroll
        for (int mi = 0; mi < 4; ++mi) {
            int rr = wr + mi * 16 + lrow;
            af[mi] = *(const short8*)(&As[rr * 32 + ((lq ^ ((rr >> 1) & 3)) << 3)]);
        }
        #pragma unroll
        for (int ni = 0; ni < 4; ++ni) {
            int rr = wc + ni * 16 + lrow;
            bf_[ni] = *(const short8*)(&Bs[rr * 32 + ((lq ^ ((rr >> 1) & 3)) << 3)]);
        }
        #pragma unroll
        for (int mi = 0; mi < 4; ++mi)
            #pragma unroll
            for (int ni = 0; ni < 4; ++ni)
                acc[mi][ni] = __builtin_amdgcn_mfma_f32_16x16x32_bf16(af[mi], bf_[ni], acc[mi][ni], 0, 0, 0);
        __syncthreads();
        cur ^= 1;
    }

    #pragma unroll
    for (int mi = 0; mi < 4; ++mi) {
        #pragma unroll
        for (int ni = 0; ni < 4; ++ni) {
            int gcol = bn * 128 + wc + ni * 16 + lrow;
            #pragma unroll
            for (int qq = 0; qq < 4; ++qq) {
                int grow = bm * 128 + wr + mi * 16 + lq * 4 + qq;
                float val = acc[mi][ni][qq];
                if constexpr (BIAS) val += bias[gcol];
                if constexpr (RELU) val = fmaxf(val, 0.f);
                if (grow >= M_real) val = 0.f;
                ((float*)Cp)[(size_t)grow * ldc + gcol] = val;
            }
        }
    }
}

// ---------------- x -> bf16 slab0 AND x_aug -> bf16 slab1 ----------------
__global__ void convert_both_k(const float* __restrict__ x, const float* __restrict__ noise,
                               unsigned short* __restrict__ out)
{
    __shared__ float sred[4];
    __shared__ float srn;
    int row = blockIdx.x, t = threadIdx.x;
    int kc = t * 8;
    f32x4 n0 = {}, n1 = {};
    float ss = 0.f;
    if (t < 250) {
        n0 = *(const f32x4*)(noise + (size_t)row * NUM_GENE + kc);
        n1 = *(const f32x4*)(noise + (size_t)row * NUM_GENE + kc + 4);
        ss = n0.x*n0.x + n0.y*n0.y + n0.z*n0.z + n0.w*n0.w
           + n1.x*n1.x + n1.y*n1.y + n1.z*n1.z + n1.w*n1.w;
    }
    for (int off = 32; off; off >>= 1) ss += __shfl_down(ss, off);
    if ((t & 63) == 0) sred[t >> 6] = ss;
    __syncthreads();
    if (t == 0) srn = 1.f / fmaxf(sqrtf(sred[0] + sred[1] + sred[2] + sred[3]), 1e-12f);
    __syncthreads();
    if (t >= 250) return;
    float rn = srn;
    f32x4 a0 = *(const f32x4*)(x + (size_t)row * NUM_GENE + kc);
    f32x4 a1 = *(const f32x4*)(x + (size_t)row * NUM_GENE + kc + 4);
    short8 v0, v1;
    #pragma unroll
    for (int i = 0; i < 4; ++i) {
        v0[i]     = (short)f2bf(a0[i]);
        v0[4 + i] = (short)f2bf(a1[i]);
        v1[i]     = (short)f2bf(a0[i] + n0[i] * rn);
        v1[4 + i] = (short)f2bf(a1[i] + n1[i] * rn);
    }
    *(short8*)(out + (size_t)row * KPAD_G + kc) = v0;
    *(short8*)(out + (size_t)(M_PAD + row) * KPAD_G + kc) = v1;
}

// ---------------- transpose + fp32->bf16 (+K pad zeroed) ----------------
__global__ void transpose_bf_k(const float* __restrict__ in, unsigned short* __restrict__ out,
                               int R, int C, int Kpad)
{
    __shared__ float tile[32][33];
    int tx = threadIdx.x & 31, ty = threadIdx.x >> 5;
    int c0 = blockIdx.x * 32, r0 = blockIdx.y * 32;
    #pragma unroll
    for (int i = 0; i < 4; ++i) {
        int r = r0 + ty + i * 8, c = c0 + tx;
        tile[ty + i * 8][tx] = (r < R && c < C) ? in[(size_t)r * C + c] : 0.f;
    }
    __syncthreads();
    #pragma unroll
    for (int i = 0; i < 4; ++i) {
        int c = c0 + ty + i * 8;
        int r = r0 + tx;
        if (c < C && r < Kpad) out[(size_t)c * Kpad + r] = f2bf(tile[tx][ty + i * 8]);
    }
}

// ---------------- CSR build by dst ----------------
__global__ void hist_k(const int* __restrict__ ei, int* __restrict__ cnt)
{
    int e = blockIdx.x * 256 + threadIdx.x;
    if (e >= E_TOT) return;
    int d = (e < N_EDGESC) ? ei[N_EDGESC + e] : (e - N_EDGESC);
    atomicAdd(&cnt[d], 1);
}

__global__ void scan_k(const int* __restrict__ cnt, int* __restrict__ rowp, int* __restrict__ cursor)
{
    __shared__ int buf[1024];
    int t = threadIdx.x;
    int loc[10];
    int s = 0, base = t * 10;
    #pragma unroll
    for (int i = 0; i < 10; ++i) {
        int idx = base + i;
        int v = (idx < N_NODESC) ? cnt[idx] : 0;
        loc[i] = v; s += v;
    }
    buf[t] = s; __syncthreads();
    for (int off = 1; off < 1024; off <<= 1) {
        int tmp = (t >= off) ? buf[t - off] : 0;
        __syncthreads();
        buf[t] += tmp;
        __syncthreads();
    }
    int run = buf[t] - s;
    #pragma unroll
    for (int i = 0; i < 10; ++i) {
        int idx = base + i;
        if (idx < N_NODESC) { rowp[idx] = run; cursor[idx] = run; run += loc[i]; }
    }
    if (t == 1023) rowp[N_NODESC] = buf[1023];
}

__global__ void scatter_k(const int* __restrict__ ei, int* __restrict__ cursor,
                          int* __restrict__ col_src, int* __restrict__ dst_of)
{
    int e = blockIdx.x * 256 + threadIdx.x;
    if (e >= E_TOT) return;
    int s, d;
    if (e < N_EDGESC) { s = ei[e]; d = ei[N_EDGESC + e]; } else { s = d = e - N_EDGESC; }
    int pos = atomicAdd(&cursor[d], 1);
    col_src[pos] = s;
    dst_of[pos] = d;
}

// ---------------- attention scores for both passes; 320 thr = 2 nodes ----------------
__global__ void escores2_k(const unsigned short* __restrict__ h,
                           const float* __restrict__ a_src, const float* __restrict__ a_dst,
                           float* __restrict__ e_s, float* __restrict__ e_d)
{
    int t = threadIdx.x;
    int half = (t >= 160);
    int tl = t - half * 160;
    int node2 = blockIdx.x * 2 + half;
    int p = node2 >= N_NODESC;
    int n = node2 - p * N_NODESC;
    int hh = tl >> 4, c = tl & 15;
    int off = hh * 128 + c * 8;
    short8 v = *(const short8*)(h + (size_t)(p * M_PAD + n) * F1 + off);
    float ps = 0.f, pd = 0.f;
    #pragma unroll
    for (int j = 0; j < 8; ++j) {
        float f = bf2f((unsigned short)v[j]);
        ps += f * a_src[off + j];
        pd += f * a_dst[off + j];
    }
    #pragma unroll
    for (int m = 1; m < 16; m <<= 1) {
        ps += __shfl_xor(ps, m, 16);
        pd += __shfl_xor(pd, m, 16);
    }
    if (c == 0) { e_s[node2 * HEADS + hh] = ps; e_d[node2 * HEADS + hh] = pd; }
}

// ---------------- per-edge alpha -> TRANSPOSED layout [pass][head][E] ----------------
__global__ void alpha_k(const int* __restrict__ colsrc, const int* __restrict__ dstof,
                        const float* __restrict__ e_s, const float* __restrict__ e_d,
                        float* __restrict__ alpha)
{
    int gid = blockIdx.x * 256 + threadIdx.x;
    if (gid >= 2 * E_TOT) return;
    int p = gid >= E_TOT;
    int e = gid - p * E_TOT;
    int s = colsrc[e], d = dstof[e];
    const float* er = e_s + (size_t)(p * N_NODESC + s) * HEADS;
    const float* dr = e_d + (size_t)(p * N_NODESC + d) * HEADS;
    #pragma unroll
    for (int h = 0; h < HEADS; ++h) {
        float a = er[h] + dr[h];
        a = a >= 0.f ? a : 0.2f * a;
        alpha[((size_t)p * HEADS + h) * E_TOT + e] = a;
    }
}

// ---------------- per-(pass,node,head) online max/sum ----------------
__global__ void nodems_k(const int* __restrict__ rowp, const float* __restrict__ alpha,
                         float2* __restrict__ minv)
{
    int gid = blockIdx.x * 256 + threadIdx.x;
    if (gid >= 2 * N_NODESC * HEADS) return;
    int p = gid >= N_NODESC * HEADS;
    int rr = gid - p * N_NODESC * HEADS;
    int n = rr / HEADS, hh = rr - n * HEADS;
    int beg = rowp[n], end = rowp[n + 1];
    const float* ap = alpha + ((size_t)p * HEADS + hh) * E_TOT;
    float m = -1e30f, ssum = 0.f;
    for (int e = beg; e < end; ++e) {
        float a = ap[e];
        if (a > m) { ssum = ssum * __expf(m - a) + 1.f; m = a; }
        else ssum += __expf(a - m);
    }
    float2 qo; qo.x = m; qo.y = 1.f / ssum;
    minv[gid] = qo;
}

// ---------------- per-edge softmax weight, in-place on transposed alpha ----------------
__global__ void wexp_k(const int* __restrict__ dstof, const float2* __restrict__ minv,
                       float* __restrict__ alpha)
{
    int gid = blockIdx.x * 256 + threadIdx.x;
    if (gid >= 2 * E_TOT) return;
    int p = gid >= E_TOT;
    int e = gid - p * E_TOT;
    int d = dstof[e];
    const float2* mv = minv + (size_t)(p * N_NODESC + d) * HEADS;
    #pragma unroll
    for (int h = 0; h < HEADS; ++h) {
        float2 qv = mv[h];
        size_t o = ((size_t)p * HEADS + h) * E_TOT + e;
        alpha[o] = __expf(alpha[o] - qv.x) * qv.y;
    }
}

// ---------------- sliced aggregation, XCD-chunked ----------------
template<int L1MODE>
__global__ void agg_slice_k(const int* __restrict__ rowp, const int* __restrict__ colsrc,
                            const float* __restrict__ alpha,
                            const unsigned short* __restrict__ h,
                            const float* __restrict__ bias,
                            unsigned short* __restrict__ out)
{
    const int nwg = gridDim.x;             // 12500
    const int q = nwg >> 3, r = nwg & 7;
    const int xcd = blockIdx.x & 7, idx = blockIdx.x >> 3;
    const int wgid = (xcd < r ? xcd * (q + 1) : r * (q + 1) + (xcd - r) * q) + idx;
    int ps = wgid / 625, nb = wgid - ps * 625;
    int p = ps / HEADS, s = ps - p * HEADS;
    int t = threadIdx.x;
    int nl = t >> 4, l16 = t & 15;
    int n = nb * 16 + nl;
    int beg = rowp[n], end = rowp[n + 1];
    const unsigned short* hb = h + (size_t)p * M_PAD * F1 + s * 128 + l16 * 8;
    const float* wb = alpha + ((size_t)p * HEADS + s) * E_TOT;
    float acc[8] = {};
    for (int e = beg; e < end; ++e) {
        int src = colsrc[e];
        float wv = wb[e];
        short8 rv = *(const short8*)(hb + (size_t)src * F1);
        #pragma unroll
        for (int j = 0; j < 8; ++j) acc[j] += wv * bf2f((unsigned short)rv[j]);
    }
    short8 o;
    if constexpr (L1MODE) {
        #pragma unroll
        for (int j = 0; j < 8; ++j)
            o[j] = (short)f2bf(fmaxf(acc[j] + bias[s * 128 + l16 * 8 + j], 0.f));
    } else {
        #pragma unroll
        for (int j = 0; j < 8; ++j) o[j] = (short)f2bf(acc[j]);
    }
    *(short8*)(out + (size_t)(p * M_PAD + n) * F1 + s * 128 + l16 * 8) = o;
}

// ---------------- head-mean + bias + relu ----------------
__global__ void headmean_k(const unsigned short* __restrict__ tmp, const float* __restrict__ b2,
                           float* __restrict__ out)
{
    int gid = blockIdx.x * 256 + threadIdx.x;
    int pn = gid >> 4, d8 = (gid & 15) * 8;
    int p = pn >= N_NODESC;
    int n = pn - p * N_NODESC;
    const unsigned short* tp = tmp + (size_t)(p * M_PAD + n) * F1 + d8;
    float acc[8] = {};
    #pragma unroll
    for (int hh = 0; hh < HEADS; ++hh) {
        short8 v = *(const short8*)(tp + hh * 128);
        #pragma unroll
        for (int j = 0; j < 8; ++j) acc[j] += bf2f((unsigned short)v[j]);
    }
    float* op = out + (size_t)(p * M_PAD + n) * LATENTC + d8;
    #pragma unroll
    for (int j = 0; j < 8; ++j) op[j] = fmaxf(acc[j] * 0.1f + b2[d8 + j], 0.f);
}

// ---------------- column sums for pooling ----------------
__global__ void colsum_k(const float* __restrict__ g01, const float* __restrict__ g2,
                         float* __restrict__ gsum)
{
    int v = blockIdx.x / 40, b = blockIdx.x % 40;
    const float* src = (v == 0) ? g01 : (v == 1) ? g01 + (size_t)M_PAD * 128 : g2;
    int t = threadIdx.x, col = t & 127, ro = t >> 7;
    int rend = min((b + 1) * 250, N_NODESC);
    float acc = 0.f;
    for (int r = b * 250 + ro; r < rend; r += 2) acc += src[(size_t)r * 128 + col];
    __shared__ float part[256];
    part[t] = acc; __syncthreads();
    if (t < 128) atomicAdd(&gsum[v * 128 + col], part[t] + part[t + 128]);
}

// ---------------- contrastive loss scalar ----------------
__global__ void loss_k(const float* __restrict__ gsum, float* __restrict__ out)
{
    int t = threadIdx.x;   // 128
    float g0 = gsum[t] * 1e-4f, g1 = gsum[128 + t] * 1e-4f, g2 = gsum[256 + t] * 1e-4f;
    float d01 = g0 * g1, d02 = g0 * g2, d12 = g1 * g2;
    for (int off = 32; off; off >>= 1) {
        d01 += __shfl_down(d01, off); d02 += __shfl_down(d02, off); d12 += __shfl_down(d12, off);
    }
    __shared__ float s[3][2];
    if ((t & 63) == 0) { int w = t >> 6; s[0][w] = d01; s[1][w] = d02; s[2][w] = d12; }
    __syncthreads();
    if (t == 0) {
        float a01 = (s[0][0] + s[0][1]) * 5.f;
        float a02 = (s[1][0] + s[1][1]) * 5.f;
        float a12 = (s[2][0] + s[2][1]) * 5.f;
        float m = fmaxf(a01, fmaxf(a02, a12));
        float se = expf(a01 - m) + expf(a02 - m) + expf(a12 - m);
        *out = -((a01 - m) - logf(se)) / 2.302585092994046f;
    }
}

// ---------------- projection heads ----------------
__global__ void proj_k(const float* __restrict__ g01, const float* __restrict__ g2,
                       const float* __restrict__ Wf, const float* __restrict__ bfv,
                       const float* __restrict__ Wc, const float* __restrict__ bc,
                       float* __restrict__ out)
{
    __shared__ float rowb[4][128];
    int m = blockIdx.y;
    const float* gx = (m == 0) ? g01 : (m == 1) ? g01 + (size_t)M_PAD * 128 : g2;
    float* out_node = out + (size_t)m * 640000;
    float* out_c = (m == 0) ? out + 1920001 : (m == 1) ? out + 2070001 : nullptr;
    int wid = threadIdx.x >> 6, l = threadIdx.x & 63;
    int n = blockIdx.x * 4 + wid;
    if (n >= N_NODESC) return;
    rowb[wid][l]      = gx[(size_t)n * 128 + l];
    rowb[wid][l + 64] = gx[(size_t)n * 128 + 64 + l];
    float acc = bfv[l];
    #pragma unroll 8
    for (int k = 0; k < 128; ++k) acc += rowb[wid][k] * Wf[k * 64 + l];
    out_node[(size_t)n * 64 + l] = acc;
    if (out_c != nullptr && l < CLUST) {
        float a2 = bc[l];
        #pragma unroll 8
        for (int k = 0; k < 128; ++k) a2 += rowb[wid][k] * Wc[k * CLUST + l];
        out_c[(size_t)l * N_NODESC + n] = a2;
    }
}

// ---------------- host ----------------
extern "C" void kernel_launch(void* const* d_in, const int* in_sizes, int n_in,
                              void* d_out, int out_size, void* d_ws, size_t ws_size,
                              hipStream_t stream)
{
    const float* x     = (const float*)d_in[0];
    const int*   ei    = (const int*)  d_in[1];
    const float* noise = (const float*)d_in[2];
    const float* W1    = (const float*)d_in[3];
    const float* a1s   = (const float*)d_in[4];
    const float* a1d   = (const float*)d_in[5];
    const float* b1    = (const float*)d_in[6];
    const float* W2    = (const float*)d_in[7];
    const float* a2s   = (const float*)d_in[8];
    const float* a2d   = (const float*)d_in[9];
    const float* b2    = (const float*)d_in[10];
    const float* Wm1   = (const float*)d_in[11];
    const float* bm1   = (const float*)d_in[12];
    const float* Wm2   = (const float*)d_in[13];
    const float* bm2   = (const float*)d_in[14];
    const float* Wf    = (const float*)d_in[15];
    const float* bfv   = (const float*)d_in[16];
    const float* Wc    = (const float*)d_in[17];
    const float* bc    = (const float*)d_in[18];
    float* out = (float*)d_out;

    size_t off = 0;
    auto alloc = [&](size_t bytes) { size_t o = off; off = (off + bytes + 255) & ~(size_t)255; return o; };
    char* ws = (char*)d_ws;
    unsigned short* xbuf2  = (unsigned short*)(ws + alloc((size_t)2 * M_PAD * KPAD_G * 2)); // later h1x2 / agg2 tmp
    unsigned short* hraw2  = (unsigned short*)(ws + alloc((size_t)2 * M_PAD * F1 * 2));
    unsigned short* w1t    = (unsigned short*)(ws + alloc((size_t)1536 * KPAD_G * 2));      // W1^T ++ Wm1^T ++ zeros
    unsigned short* w2t    = (unsigned short*)(ws + alloc((size_t)F1 * F1 * 2));
    unsigned short* wm2t   = (unsigned short*)(ws + alloc((size_t)128 * 128 * 2));
    unsigned short* t_bf   = (unsigned short*)(ws + alloc((size_t)M_PAD * 128 * 2));
    float*  alpha  = (float*) (ws + alloc((size_t)2 * E_TOT * HEADS * 4));
    float2* minv   = (float2*)(ws + alloc((size_t)2 * N_NODESC * HEADS * 8));
    float*  es     = (float*) (ws + alloc((size_t)2 * N_NODESC * HEADS * 4));
    float*  edv    = (float*) (ws + alloc((size_t)2 * N_NODESC * HEADS * 4));
    int*    cnt    = (int*)   (ws + alloc((size_t)N_NODESC * 4));
    int*    rowp   = (int*)   (ws + alloc((size_t)(N_NODESC + 16) * 4));
    int*    cursor = (int*)   (ws + alloc((size_t)N_NODESC * 4));
    int*    colsrc = (int*)   (ws + alloc((size_t)E_TOT * 4));
    int*    dstof  = (int*)   (ws + alloc((size_t)E_TOT * 4));
    float*  gx01   = (float*) (ws + alloc((size_t)2 * M_PAD * 128 * 4));
    float*  gx2    = (float*) (ws + alloc((size_t)M_PAD * 128 * 4));
    float*  gsum   = (float*) (ws + alloc((size_t)384 * 4));
    unsigned short* h1x2 = xbuf2;        // alias: xbuf2 dead after L1 GEMM
    unsigned short* tmp2 = xbuf2;        // alias: h1x2 dead after L2 GEMM
    (void)ws_size; (void)in_sizes; (void)n_in; (void)out_size;

    hipMemsetAsync(cnt, 0, (size_t)N_NODESC * 4, stream);
    hipMemsetAsync(gsum, 0, 384 * 4, stream);
    hipMemsetAsync(w1t + (size_t)1408 * KPAD_G, 0, (size_t)128 * KPAD_G * 2, stream);  // zero-pad B rows

    convert_both_k<<<N_NODESC, 256, 0, stream>>>(x, noise, xbuf2);

    transpose_bf_k<<<dim3(40, 64), 256, 0, stream>>>(W1,  w1t,  NUM_GENE, F1,  KPAD_G);
    transpose_bf_k<<<dim3(4, 64),  256, 0, stream>>>(Wm1, w1t + (size_t)1280 * KPAD_G, NUM_GENE, 128, KPAD_G);
    transpose_bf_k<<<dim3(40, 40), 256, 0, stream>>>(W2,  w2t,  F1,       F1,  F1);
    transpose_bf_k<<<dim3(4, 4),   256, 0, stream>>>(Wm2, wm2t, 128,      128, 128);

    hist_k   <<<(E_TOT + 255) / 256, 256, 0, stream>>>(ei, cnt);
    scan_k   <<<1, 1024, 0, stream>>>(cnt, rowp, cursor);
    scatter_k<<<(E_TOT + 255) / 256, 256, 0, stream>>>(ei, cursor, colsrc, dstof);

    // ---- L1 GEMM with folded MLP layer 1 (N = 1536 = 6 tiles) ----
    gemm256<0,1><<<RT_TILES * 6, 512, 0, stream>>>(xbuf2, KPAD_G, w1t, KPAD_G,
        hraw2, F1, 32, 6, N_NODESC, bm1, t_bf);
    // MLP layer 2 (reads t_bf produced above)
    gemm2<1,1,0><<<RT_TILES, 256, 0, stream>>>(t_bf, 128, wm2t, 128,
        bm2, gx2, 128, 4, 1, N_NODESC);

    escores2_k<<<N_NODESC, 320, 0, stream>>>(hraw2, a1s, a1d, es, edv);
    alpha_k <<<(2 * E_TOT + 255) / 256, 256, 0, stream>>>(colsrc, dstof, es, edv, alpha);
    nodems_k<<<(2 * N_NODESC * HEADS + 255) / 256, 256, 0, stream>>>(rowp, alpha, minv);
    wexp_k  <<<(2 * E_TOT + 255) / 256, 256, 0, stream>>>(dstof, minv, alpha);
    agg_slice_k<1><<<12500, 256, 0, stream>>>(rowp, colsrc, alpha, hraw2, b1, h1x2);

    gemm256<0,0><<<RT_TILES * 5, 512, 0, stream>>>(h1x2, F1, w2t, F1,
        hraw2, F1, 20, 5, N_NODESC, nullptr, nullptr);
    escores2_k<<<N_NODESC, 320, 0, stream>>>(hraw2, a2s, a2d, es, edv);
    alpha_k <<<(2 * E_TOT + 255) / 256, 256, 0, stream>>>(colsrc, dstof, es, edv, alpha);
    nodems_k<<<(2 * N_NODESC * HEADS + 255) / 256, 256, 0, stream>>>(rowp, alpha, minv);
    wexp_k  <<<(2 * E_TOT + 255) / 256, 256, 0, stream>>>(dstof, minv, alpha);
    agg_slice_k<0><<<12500, 256, 0, stream>>>(rowp, colsrc, alpha, hraw2, nullptr, tmp2);
    headmean_k<<<1250, 256, 0, stream>>>(tmp2, b2, gx01);

    colsum_k<<<120, 256, 0, stream>>>(gx01, gx2, gsum);
    loss_k  <<<1, 128, 0, stream>>>(gsum, out + 1920000);

    proj_k<<<dim3(2500, 3), 256, 0, stream>>>(gx01, gx2, Wf, bfv, Wc, bc, out);
}

// Round 13
// 583.691 us; speedup vs baseline: 1.1654x; 1.1219x over previous
//
#include <hip/hip_runtime.h>
#include <hip/hip_bf16.h>

// ---------------- problem constants ----------------
#define N_NODESC 10000
#define M_PAD    10112          // 79 * 128
#define RT_TILES 79
#define NUM_GENE 2000
#define KPAD_G   2048
#define N_EDGESC 160000
#define E_TOT    170000         // + self loops
#define HEADS    10
#define F1       1280           // HEADS*128
#define LATENTC  128
#define LOWERC   64
#define CLUST    15

typedef __attribute__((ext_vector_type(8))) short   short8;
typedef __attribute__((ext_vector_type(4))) float   f32x4;
typedef __attribute__((ext_vector_type(4))) unsigned short ushort4_;

__device__ __forceinline__ float bf2f(unsigned short u){
    unsigned int x = ((unsigned int)u) << 16;
    return __builtin_bit_cast(float, x);
}
__device__ __forceinline__ unsigned short f2bf(float f){
    __hip_bfloat16 h = __float2bfloat16(f);
    return __builtin_bit_cast(unsigned short, h);
}
__device__ __forceinline__ void gload16(const void* g, void* l) {
    __builtin_amdgcn_global_load_lds((const __attribute__((address_space(1))) void*)g,
                                     (__attribute__((address_space(3))) void*)l, 16, 0, 0);
}

// ======== 256x256 bf16 MFMA GEMM — 4-phase quadrant schedule, counted vmcnt ========
// (FROZEN: R12's proven best schedule.)
template<int OMODE, int FOLD>   // OMODE: 0 bf16 out, 1 f32 out
__global__ __launch_bounds__(512, 2)
void gemm256(const unsigned short* __restrict__ A, int lda,
             const unsigned short* __restrict__ BT, int ldb,
             void* __restrict__ Cp, int ldc,
             int NK, int NT, int M_real,
             const float* __restrict__ mbias, unsigned short* __restrict__ mout)
{
    __shared__ short smem[65536];   // 128 KiB

    const int nwg = gridDim.x;
    const int q = nwg >> 3, r = nwg & 7;
    const int xcd = blockIdx.x & 7, idx = blockIdx.x >> 3;
    const int wgid = (xcd < r ? xcd * (q + 1) : r * (q + 1) + (xcd - r) * q) + idx;
    const int bm = wgid / NT, bn = wgid - bm * NT;

    const int t = threadIdx.x, w = t >> 6, lane = t & 63;
    const int wr2 = (w >> 2) * 64;
    const int wc2 = (w & 3) * 32;
    const int lrow = lane & 15, lq = lane >> 4;

    int rowc[2], swc[2], loff[2];
    #pragma unroll
    for (int cc = 0; cc < 2; ++cc) {
        int c = cc * 512 + t;
        int row = c >> 3, slot = c & 7;
        rowc[cc] = row;
        swc[cc]  = (slot ^ (row & 7)) << 3;
        loff[cc] = c * 8;
    }
    auto stageA = [&](int buf, int h, int kt) {
        short* dst = smem + buf * 32768 + h * 8192;
        const unsigned short* src = A + (size_t)(bm * 256 + h * 128) * lda + kt * 64;
        #pragma unroll
        for (int cc = 0; cc < 2; ++cc)
            gload16(src + (size_t)rowc[cc] * lda + swc[cc], dst + loff[cc]);
    };
    auto stageB = [&](int buf, int h, int kt) {
        short* dst = smem + buf * 32768 + 16384 + h * 8192;
        const unsigned short* src = BT + (size_t)(bn * 256 + h * 128) * ldb + kt * 64;
        #pragma unroll
        for (int cc = 0; cc < 2; ++cc)
            gload16(src + (size_t)rowc[cc] * ldb + swc[cc], dst + loff[cc]);
    };
    auto rdA = [&](int buf, int h, int mi, int ks) -> short8 {
        int r7 = wr2 + mi * 16 + lrow;
        return *(const short8*)(smem + buf * 32768 + h * 8192 + r7 * 64
                                + (((ks * 4 + lq) ^ (r7 & 7)) << 3));
    };
    auto rdB = [&](int buf, int h, int ni, int ks) -> short8 {
        int r7 = wc2 + ni * 16 + lrow;
        return *(const short8*)(smem + buf * 32768 + 16384 + h * 8192 + r7 * 64
                                + (((ks * 4 + lq) ^ (r7 & 7)) << 3));
    };

    f32x4 acc00[4][2] = {}, acc01[4][2] = {}, acc10[4][2] = {}, acc11[4][2] = {};
    short8 a0[4][2], a1[4][2], b0[2][2], b1[2][2];

    auto domfma = [&](f32x4 (&ac)[4][2], short8 (&aa)[4][2], short8 (&bb)[2][2]) {
        __builtin_amdgcn_s_setprio(1);
        #pragma unroll
        for (int mi = 0; mi < 4; ++mi)
            #pragma unroll
            for (int ni = 0; ni < 2; ++ni)
                #pragma unroll
                for (int ks = 0; ks < 2; ++ks)
                    ac[mi][ni] = __builtin_amdgcn_mfma_f32_16x16x32_bf16(
                        aa[mi][ks], bb[ni][ks], ac[mi][ni], 0, 0, 0);
        __builtin_amdgcn_s_setprio(0);
    };

    stageA(0, 0, 0); stageB(0, 0, 0); stageB(0, 1, 0); stageA(0, 1, 0);

    for (int kt = 0; kt < NK; ++kt) {
        const int buf = kt & 1, nbuf = buf ^ 1;
        const bool pf = (kt + 1 < NK);
        asm volatile("s_waitcnt vmcnt(4)" ::: "memory");
        __builtin_amdgcn_sched_barrier(0);
        __builtin_amdgcn_s_barrier();
        __builtin_amdgcn_sched_barrier(0);
        #pragma unroll
        for (int mi = 0; mi < 4; ++mi) { a0[mi][0] = rdA(buf, 0, mi, 0); a0[mi][1] = rdA(buf, 0, mi, 1); }
        #pragma unroll
        for (int ni = 0; ni < 2; ++ni) { b0[ni][0] = rdB(buf, 0, ni, 0); b0[ni][1] = rdB(buf, 0, ni, 1); }
        if (pf) { stageA(nbuf, 0, kt + 1); stageB(nbuf, 0, kt + 1); }
        domfma(acc00, a0, b0);
        if (pf) { asm volatile("s_waitcnt vmcnt(4)" ::: "memory"); }
        else    { asm volatile("s_waitcnt vmcnt(0)" ::: "memory"); }
        __builtin_amdgcn_sched_barrier(0);
        __builtin_amdgcn_s_barrier();
        __builtin_amdgcn_sched_barrier(0);
        #pragma unroll
        for (int ni = 0; ni < 2; ++ni) { b1[ni][0] = rdB(buf, 1, ni, 0); b1[ni][1] = rdB(buf, 1, ni, 1); }
        if (pf) stageB(nbuf, 1, kt + 1);
        domfma(acc01, a0, b1);
        #pragma unroll
        for (int mi = 0; mi < 4; ++mi) { a1[mi][0] = rdA(buf, 1, mi, 0); a1[mi][1] = rdA(buf, 1, mi, 1); }
        if (pf) stageA(nbuf, 1, kt + 1);
        domfma(acc10, a1, b0);
        domfma(acc11, a1, b1);
    }

    const bool mlp_tile = FOLD && (bn == NT - 1);
    #pragma unroll
    for (int qa = 0; qa < 2; ++qa) {
        #pragma unroll
        for (int qb = 0; qb < 2; ++qb) {
            f32x4 (&ac)[4][2] = (qa == 0) ? (qb == 0 ? acc00 : acc01)
                                          : (qb == 0 ? acc10 : acc11);
            if (mlp_tile) {
                if (qb != 0) continue;
                #pragma unroll
                for (int mi = 0; mi < 4; ++mi) {
                    #pragma unroll
                    for (int ni = 0; ni < 2; ++ni) {
                        int col = wc2 + ni * 16 + lrow;
                        #pragma unroll
                        for (int qq = 0; qq < 4; ++qq) {
                            int grow = bm * 256 + qa * 128 + wr2 + mi * 16 + lq * 4 + qq;
                            if (grow < N_NODESC) {
                                float val = fmaxf(ac[mi][ni][qq] + mbias[col], 0.f);
                                mout[(size_t)grow * 128 + col] = f2bf(val);
                            }
                        }
                    }
                }
                continue;
            }
            #pragma unroll
            for (int mi = 0; mi < 4; ++mi) {
                #pragma unroll
                for (int ni = 0; ni < 2; ++ni) {
                    int gcol = bn * 256 + qb * 128 + wc2 + ni * 16 + lrow;
                    #pragma unroll
                    for (int qq = 0; qq < 4; ++qq) {
                        int grow = bm * 256 + qa * 128 + wr2 + mi * 16 + lq * 4 + qq;
                        float val = ac[mi][ni][qq];
                        int rslab = grow >= M_PAD ? grow - M_PAD : grow;
                        if (rslab >= M_real) val = 0.f;
                        if constexpr (OMODE == 0)
                            ((unsigned short*)Cp)[(size_t)grow * ldc + gcol] = f2bf(val);
                        else
                            ((float*)Cp)[(size_t)grow * ldc + gcol] = val;
                    }
                }
            }
        }
    }
}

// ---------------- 128x128 bf16 GEMM (MLP2), dbuf 2-phase ----------------
template<int OMODE, int BIAS, int RELU>
__global__ __launch_bounds__(256)
void gemm2(const unsigned short* __restrict__ A, int lda,
           const unsigned short* __restrict__ BT, int ldb,
           const float* __restrict__ bias,
           void* __restrict__ Cp, int ldc,
           int KT, int NT, int M_real)
{
    __shared__ short smem[16384];

    const int nwg = gridDim.x;
    const int q = nwg >> 3, r = nwg & 7;
    const int xcd = blockIdx.x & 7, idx = blockIdx.x >> 3;
    const int wgid = (xcd < r ? xcd * (q + 1) : r * (q + 1) + (xcd - r) * q) + idx;
    const int bm = wgid / NT, bn = wgid - bm * NT;

    const int t = threadIdx.x, w = t >> 6, lane = t & 63;
    const int wr = (w >> 1) * 64, wc = (w & 1) * 64;
    const int lrow = lane & 15, lq = lane >> 4;

    const unsigned short* Ag[2];
    const unsigned short* Bg[2];
    int lds_off[2];
    #pragma unroll
    for (int cc = 0; cc < 2; ++cc) {
        int c = cc * 256 + t;
        int row = c >> 2, slot = c & 3;
        int gk = (slot ^ ((row >> 1) & 3)) << 3;
        Ag[cc] = A  + (size_t)(bm * 128 + row) * lda + gk;
        Bg[cc] = BT + (size_t)(bn * 128 + row) * ldb + gk;
        lds_off[cc] = cc * 2048 + w * 512 + lane * 8;
    }

    auto stage = [&](int buf, int kt) {
        const int kk = kt * 32;
        #pragma unroll
        for (int cc = 0; cc < 2; ++cc) {
            gload16(Ag[cc] + kk, smem + buf * 8192 + lds_off[cc]);
            gload16(Bg[cc] + kk, smem + buf * 8192 + 4096 + lds_off[cc]);
        }
    };

    f32x4 acc[4][4] = {};
    stage(0, 0);
    __syncthreads();
    int cur = 0;
    for (int kt = 0; kt < KT; ++kt) {
        if (kt + 1 < KT) stage(cur ^ 1, kt + 1);
        const short* As = smem + cur * 8192;
        const short* Bs = As + 4096;
        short8 af[4], bf_[4];
        #pragma unroll
        for (int mi = 0; mi < 4; ++mi) {
            int rr = wr + mi * 16 + lrow;
            af[mi] = *(const short8*)(&As[rr * 32 + ((lq ^ ((rr >> 1) & 3)) << 3)]);
        }
        #pragma unroll
        for (int ni = 0; ni < 4; ++ni) {
            int rr = wc + ni * 16 + lrow;
            bf_[ni] = *(const short8*)(&Bs[rr * 32 + ((lq ^ ((rr >> 1) & 3)) << 3)]);
        }
        #pragma unroll
        for (int mi = 0; mi < 4; ++mi)
            #pragma unroll
            for (int ni = 0; ni < 4; ++ni)
                acc[mi][ni] = __builtin_amdgcn_mfma_f32_16x16x32_bf16(af[mi], bf_[ni], acc[mi][ni], 0, 0, 0);
        __syncthreads();
        cur ^= 1;
    }

    #pragma unroll
    for (int mi = 0; mi < 4; ++mi) {
        #pragma unroll
        for (int ni = 0; ni < 4; ++ni) {
            int gcol = bn * 128 + wc + ni * 16 + lrow;
            #pragma unroll
            for (int qq = 0; qq < 4; ++qq) {
                int grow = bm * 128 + wr + mi * 16 + lq * 4 + qq;
                float val = acc[mi][ni][qq];
                if constexpr (BIAS) val += bias[gcol];
                if constexpr (RELU) val = fmaxf(val, 0.f);
                if (grow >= M_real) val = 0.f;
                ((float*)Cp)[(size_t)grow * ldc + gcol] = val;
            }
        }
    }
}

// ---------------- fused prologue: convert_both + 4 transposes + hist ----------------
__device__ __forceinline__ void convert_body(const float* __restrict__ x,
                                             const float* __restrict__ noise,
                                             unsigned short* __restrict__ out, int row)
{
    __shared__ float sred[4];
    __shared__ float srn;
    int t = threadIdx.x;
    int kc = t * 8;
    f32x4 n0 = {}, n1 = {};
    float ss = 0.f;
    if (t < 250) {
        n0 = *(const f32x4*)(noise + (size_t)row * NUM_GENE + kc);
        n1 = *(const f32x4*)(noise + (size_t)row * NUM_GENE + kc + 4);
        ss = n0.x*n0.x + n0.y*n0.y + n0.z*n0.z + n0.w*n0.w
           + n1.x*n1.x + n1.y*n1.y + n1.z*n1.z + n1.w*n1.w;
    }
    for (int off = 32; off; off >>= 1) ss += __shfl_down(ss, off);
    if ((t & 63) == 0) sred[t >> 6] = ss;
    __syncthreads();
    if (t == 0) srn = 1.f / fmaxf(sqrtf(sred[0] + sred[1] + sred[2] + sred[3]), 1e-12f);
    __syncthreads();
    if (t >= 250) return;
    float rn = srn;
    f32x4 a0 = *(const f32x4*)(x + (size_t)row * NUM_GENE + kc);
    f32x4 a1 = *(const f32x4*)(x + (size_t)row * NUM_GENE + kc + 4);
    short8 v0, v1;
    #pragma unroll
    for (int i = 0; i < 4; ++i) {
        v0[i]     = (short)f2bf(a0[i]);
        v0[4 + i] = (short)f2bf(a1[i]);
        v1[i]     = (short)f2bf(a0[i] + n0[i] * rn);
        v1[4 + i] = (short)f2bf(a1[i] + n1[i] * rn);
    }
    *(short8*)(out + (size_t)row * KPAD_G + kc) = v0;
    *(short8*)(out + (size_t)(M_PAD + row) * KPAD_G + kc) = v1;
}

__device__ __forceinline__ void transpose_body(const float* __restrict__ in,
                                               unsigned short* __restrict__ out,
                                               int R, int C, int Kpad, int bx, int by)
{
    __shared__ float tile[32][33];
    int tx = threadIdx.x & 31, ty = threadIdx.x >> 5;
    int c0 = bx * 32, r0 = by * 32;
    #pragma unroll
    for (int i = 0; i < 4; ++i) {
        int r = r0 + ty + i * 8, c = c0 + tx;
        tile[ty + i * 8][tx] = (r < R && c < C) ? in[(size_t)r * C + c] : 0.f;
    }
    __syncthreads();
    #pragma unroll
    for (int i = 0; i < 4; ++i) {
        int c = c0 + ty + i * 8;
        int r = r0 + tx;
        if (c < C && r < Kpad) out[(size_t)c * Kpad + r] = f2bf(tile[tx][ty + i * 8]);
    }
}

__global__ void prologue_k(const float* __restrict__ x, const float* __restrict__ noise,
                           unsigned short* __restrict__ xbuf,
                           const float* __restrict__ W1, const float* __restrict__ Wm1,
                           const float* __restrict__ W2, const float* __restrict__ Wm2,
                           unsigned short* __restrict__ w1t, unsigned short* __restrict__ w2t,
                           unsigned short* __restrict__ wm2t,
                           const int* __restrict__ ei, int* __restrict__ cnt)
{
    int b = blockIdx.x;
    if (b < 10000) { convert_body(x, noise, xbuf, b); return; }
    b -= 10000;
    if (b < 2560) { transpose_body(W1, w1t, NUM_GENE, F1, KPAD_G, b % 40, b / 40); return; }
    b -= 2560;
    if (b < 256)  { transpose_body(Wm1, w1t + (size_t)1280 * KPAD_G, NUM_GENE, 128, KPAD_G, b % 4, b / 4); return; }
    b -= 256;
    if (b < 1600) { transpose_body(W2, w2t, F1, F1, F1, b % 40, b / 40); return; }
    b -= 1600;
    if (b < 16)   { transpose_body(Wm2, wm2t, 128, 128, 128, b % 4, b / 4); return; }
    b -= 16;
    int e = b * 256 + threadIdx.x;
    if (e < E_TOT) {
        int d = (e < N_EDGESC) ? ei[N_EDGESC + e] : (e - N_EDGESC);
        atomicAdd(&cnt[d], 1);
    }
}
#define PROLOGUE_BLOCKS (10000 + 2560 + 256 + 1600 + 16 + 665)

// ---------------- CSR scan + scatter ----------------
__global__ void scan_k(const int* __restrict__ cnt, int* __restrict__ rowp, int* __restrict__ cursor)
{
    __shared__ int buf[1024];
    int t = threadIdx.x;
    int loc[10];
    int s = 0, base = t * 10;
    #pragma unroll
    for (int i = 0; i < 10; ++i) {
        int idx = base + i;
        int v = (idx < N_NODESC) ? cnt[idx] : 0;
        loc[i] = v; s += v;
    }
    buf[t] = s; __syncthreads();
    for (int off = 1; off < 1024; off <<= 1) {
        int tmp = (t >= off) ? buf[t - off] : 0;
        __syncthreads();
        buf[t] += tmp;
        __syncthreads();
    }
    int run = buf[t] - s;
    #pragma unroll
    for (int i = 0; i < 10; ++i) {
        int idx = base + i;
        if (idx < N_NODESC) { rowp[idx] = run; cursor[idx] = run; run += loc[i]; }
    }
    if (t == 1023) rowp[N_NODESC] = buf[1023];
}

__global__ void scatter_k(const int* __restrict__ ei, int* __restrict__ cursor,
                          int* __restrict__ col_src, int* __restrict__ dst_of)
{
    int e = blockIdx.x * 256 + threadIdx.x;
    if (e >= E_TOT) return;
    int s, d;
    if (e < N_EDGESC) { s = ei[e]; d = ei[N_EDGESC + e]; } else { s = d = e - N_EDGESC; }
    int pos = atomicAdd(&cursor[d], 1);
    col_src[pos] = s;
    dst_of[pos] = d;
}

// ---------------- attention scores for both passes; 320 thr = 2 nodes ----------------
__global__ void escores2_k(const unsigned short* __restrict__ h,
                           const float* __restrict__ a_src, const float* __restrict__ a_dst,
                           float* __restrict__ e_s, float* __restrict__ e_d)
{
    int t = threadIdx.x;
    int half = (t >= 160);
    int tl = t - half * 160;
    int node2 = blockIdx.x * 2 + half;
    int p = node2 >= N_NODESC;
    int n = node2 - p * N_NODESC;
    int hh = tl >> 4, c = tl & 15;
    int off = hh * 128 + c * 8;
    short8 v = *(const short8*)(h + (size_t)(p * M_PAD + n) * F1 + off);
    float ps = 0.f, pd = 0.f;
    #pragma unroll
    for (int j = 0; j < 8; ++j) {
        float f = bf2f((unsigned short)v[j]);
        ps += f * a_src[off + j];
        pd += f * a_dst[off + j];
    }
    #pragma unroll
    for (int m = 1; m < 16; m <<= 1) {
        ps += __shfl_xor(ps, m, 16);
        pd += __shfl_xor(pd, m, 16);
    }
    if (c == 0) { e_s[node2 * HEADS + hh] = ps; e_d[node2 * HEADS + hh] = pd; }
}

// ---------------- per-edge alpha -> TRANSPOSED layout [pass][head][E] ----------------
__global__ void alpha_k(const int* __restrict__ colsrc, const int* __restrict__ dstof,
                        const float* __restrict__ e_s, const float* __restrict__ e_d,
                        float* __restrict__ alpha)
{
    int gid = blockIdx.x * 256 + threadIdx.x;
    if (gid >= 2 * E_TOT) return;
    int p = gid >= E_TOT;
    int e = gid - p * E_TOT;
    int s = colsrc[e], d = dstof[e];
    const float* er = e_s + (size_t)(p * N_NODESC + s) * HEADS;
    const float* dr = e_d + (size_t)(p * N_NODESC + d) * HEADS;
    #pragma unroll
    for (int h = 0; h < HEADS; ++h) {
        float a = er[h] + dr[h];
        a = a >= 0.f ? a : 0.2f * a;
        alpha[((size_t)p * HEADS + h) * E_TOT + e] = a;
    }
}

// ---------------- per-(pass,node,head) online max/sum ----------------
__global__ void nodems_k(const int* __restrict__ rowp, const float* __restrict__ alpha,
                         float2* __restrict__ minv)
{
    int gid = blockIdx.x * 256 + threadIdx.x;
    if (gid >= 2 * N_NODESC * HEADS) return;
    int p = gid >= N_NODESC * HEADS;
    int rr = gid - p * N_NODESC * HEADS;
    int n = rr / HEADS, hh = rr - n * HEADS;
    int beg = rowp[n], end = rowp[n + 1];
    const float* ap = alpha + ((size_t)p * HEADS + hh) * E_TOT;
    float m = -1e30f, ssum = 0.f;
    for (int e = beg; e < end; ++e) {
        float a = ap[e];
        if (a > m) { ssum = ssum * __expf(m - a) + 1.f; m = a; }
        else ssum += __expf(a - m);
    }
    float2 qo; qo.x = m; qo.y = 1.f / ssum;
    minv[gid] = qo;
}

// ---------------- per-edge softmax weight, in-place on transposed alpha ----------------
__global__ void wexp_k(const int* __restrict__ dstof, const float2* __restrict__ minv,
                       float* __restrict__ alpha)
{
    int gid = blockIdx.x * 256 + threadIdx.x;
    if (gid >= 2 * E_TOT) return;
    int p = gid >= E_TOT;
    int e = gid - p * E_TOT;
    int d = dstof[e];
    const float2* mv = minv + (size_t)(p * N_NODESC + d) * HEADS;
    #pragma unroll
    for (int h = 0; h < HEADS; ++h) {
        float2 qv = mv[h];
        size_t o = ((size_t)p * HEADS + h) * E_TOT + e;
        alpha[o] = __expf(alpha[o] - qv.x) * qv.y;
    }
}

// ---------------- sliced aggregation, XCD-chunked, 2-deep gather pipeline ----------------
template<int L1MODE>
__global__ void agg_slice_k(const int* __restrict__ rowp, const int* __restrict__ colsrc,
                            const float* __restrict__ alpha,
                            const unsigned short* __restrict__ h,
                            const float* __restrict__ bias,
                            unsigned short* __restrict__ out)
{
    const int nwg = gridDim.x;             // 12500
    const int q = nwg >> 3, r = nwg & 7;
    const int xcd = blockIdx.x & 7, idx = blockIdx.x >> 3;
    const int wgid = (xcd < r ? xcd * (q + 1) : r * (q + 1) + (xcd - r) * q) + idx;
    int ps = wgid / 625, nb = wgid - ps * 625;
    int p = ps / HEADS, s = ps - p * HEADS;
    int t = threadIdx.x;
    int nl = t >> 4, l16 = t & 15;
    int n = nb * 16 + nl;
    int beg = rowp[n], end = rowp[n + 1];
    const unsigned short* hb = h + (size_t)p * M_PAD * F1 + s * 128 + l16 * 8;
    const float* wb = alpha + ((size_t)p * HEADS + s) * E_TOT;
    float acc[8] = {};
    int e = beg;
    if (e < end) {
        float wv = wb[e];
        short8 rv = *(const short8*)(hb + (size_t)colsrc[e] * F1);
        for (++e; e < end; ++e) {
            float wv2 = wb[e];
            short8 rv2 = *(const short8*)(hb + (size_t)colsrc[e] * F1);
            #pragma unroll
            for (int j = 0; j < 8; ++j) acc[j] += wv * bf2f((unsigned short)rv[j]);
            wv = wv2; rv = rv2;
        }
        #pragma unroll
        for (int j = 0; j < 8; ++j) acc[j] += wv * bf2f((unsigned short)rv[j]);
    }
    short8 o;
    if constexpr (L1MODE) {
        #pragma unroll
        for (int j = 0; j < 8; ++j)
            o[j] = (short)f2bf(fmaxf(acc[j] + bias[s * 128 + l16 * 8 + j], 0.f));
    } else {
        #pragma unroll
        for (int j = 0; j < 8; ++j) o[j] = (short)f2bf(acc[j]);
    }
    *(short8*)(out + (size_t)(p * M_PAD + n) * F1 + s * 128 + l16 * 8) = o;
}

// ---------------- head-mean + bias + relu ----------------
__global__ void headmean_k(const unsigned short* __restrict__ tmp, const float* __restrict__ b2,
                           float* __restrict__ out)
{
    int gid = blockIdx.x * 256 + threadIdx.x;
    int pn = gid >> 4, d8 = (gid & 15) * 8;
    int p = pn >= N_NODESC;
    int n = pn - p * N_NODESC;
    const unsigned short* tp = tmp + (size_t)(p * M_PAD + n) * F1 + d8;
    float acc[8] = {};
    #pragma unroll
    for (int hh = 0; hh < HEADS; ++hh) {
        short8 v = *(const short8*)(tp + hh * 128);
        #pragma unroll
        for (int j = 0; j < 8; ++j) acc[j] += bf2f((unsigned short)v[j]);
    }
    float* op = out + (size_t)(p * M_PAD + n) * LATENTC + d8;
    #pragma unroll
    for (int j = 0; j < 8; ++j) op[j] = fmaxf(acc[j] * 0.1f + b2[d8 + j], 0.f);
}

// ---------------- fused projection heads + column sums ----------------
__global__ void projsum_k(const float* __restrict__ g01, const float* __restrict__ g2,
                          const float* __restrict__ Wf, const float* __restrict__ bfv,
                          const float* __restrict__ Wc, const float* __restrict__ bc,
                          float* __restrict__ out, float* __restrict__ gsum)
{
    int b = blockIdx.x;
    if (b < 7500) {
        __shared__ float rowb[4][128];
        int m = b / 2500, bx = b - m * 2500;
        const float* gx = (m == 0) ? g01 : (m == 1) ? g01 + (size_t)M_PAD * 128 : g2;
        float* out_node = out + (size_t)m * 640000;
        float* out_c = (m == 0) ? out + 1920001 : (m == 1) ? out + 2070001 : nullptr;
        int wid = threadIdx.x >> 6, l = threadIdx.x & 63;
        int n = bx * 4 + wid;
        if (n >= N_NODESC) return;
        rowb[wid][l]      = gx[(size_t)n * 128 + l];
        rowb[wid][l + 64] = gx[(size_t)n * 128 + 64 + l];
        float acc = bfv[l];
        #pragma unroll 8
        for (int k = 0; k < 128; ++k) acc += rowb[wid][k] * Wf[k * 64 + l];
        out_node[(size_t)n * 64 + l] = acc;
        if (out_c != nullptr && l < CLUST) {
            float a2 = bc[l];
            #pragma unroll 8
            for (int k = 0; k < 128; ++k) a2 += rowb[wid][k] * Wc[k * CLUST + l];
            out_c[(size_t)l * N_NODESC + n] = a2;
        }
        return;
    }
    b -= 7500;                              // colsum: 120 blocks
    int v = b / 40, bb = b % 40;
    const float* src = (v == 0) ? g01 : (v == 1) ? g01 + (size_t)M_PAD * 128 : g2;
    int t = threadIdx.x, col = t & 127, ro = t >> 7;
    int rend = min((bb + 1) * 250, N_NODESC);
    float acc = 0.f;
    for (int rr = bb * 250 + ro; rr < rend; rr += 2) acc += src[(size_t)rr * 128 + col];
    __shared__ float part[256];
    part[t] = acc; __syncthreads();
    if (t < 128) atomicAdd(&gsum[v * 128 + col], part[t] + part[t + 128]);
}

// ---------------- contrastive loss scalar ----------------
__global__ void loss_k(const float* __restrict__ gsum, float* __restrict__ out)
{
    int t = threadIdx.x;   // 128
    float g0 = gsum[t] * 1e-4f, g1 = gsum[128 + t] * 1e-4f, g2 = gsum[256 + t] * 1e-4f;
    float d01 = g0 * g1, d02 = g0 * g2, d12 = g1 * g2;
    for (int off = 32; off; off >>= 1) {
        d01 += __shfl_down(d01, off); d02 += __shfl_down(d02, off); d12 += __shfl_down(d12, off);
    }
    __shared__ float s[3][2];
    if ((t & 63) == 0) { int w = t >> 6; s[0][w] = d01; s[1][w] = d02; s[2][w] = d12; }
    __syncthreads();
    if (t == 0) {
        float a01 = (s[0][0] + s[0][1]) * 5.f;
        float a02 = (s[1][0] + s[1][1]) * 5.f;
        float a12 = (s[2][0] + s[2][1]) * 5.f;
        float m = fmaxf(a01, fmaxf(a02, a12));
        float se = expf(a01 - m) + expf(a02 - m) + expf(a12 - m);
        *out = -((a01 - m) - logf(se)) / 2.302585092994046f;
    }
}

// ---------------- host ----------------
extern "C" void kernel_launch(void* const* d_in, const int* in_sizes, int n_in,
                              void* d_out, int out_size, void* d_ws, size_t ws_size,
                              hipStream_t stream)
{
    const float* x     = (const float*)d_in[0];
    const int*   ei    = (const int*)  d_in[1];
    const float* noise = (const float*)d_in[2];
    const float* W1    = (const float*)d_in[3];
    const float* a1s   = (const float*)d_in[4];
    const float* a1d   = (const float*)d_in[5];
    const float* b1    = (const float*)d_in[6];
    const float* W2    = (const float*)d_in[7];
    const float* a2s   = (const float*)d_in[8];
    const float* a2d   = (const float*)d_in[9];
    const float* b2    = (const float*)d_in[10];
    const float* Wm1   = (const float*)d_in[11];
    const float* bm1   = (const float*)d_in[12];
    const float* Wm2   = (const float*)d_in[13];
    const float* bm2   = (const float*)d_in[14];
    const float* Wf    = (const float*)d_in[15];
    const float* bfv   = (const float*)d_in[16];
    const float* Wc    = (const float*)d_in[17];
    const float* bc    = (const float*)d_in[18];
    float* out = (float*)d_out;

    size_t off = 0;
    auto alloc = [&](size_t bytes) { size_t o = off; off = (off + bytes + 255) & ~(size_t)255; return o; };
    char* ws = (char*)d_ws;
    unsigned short* xbuf2  = (unsigned short*)(ws + alloc((size_t)2 * M_PAD * KPAD_G * 2)); // later h1x2 / agg2 tmp
    unsigned short* hraw2  = (unsigned short*)(ws + alloc((size_t)2 * M_PAD * F1 * 2));
    unsigned short* w1t    = (unsigned short*)(ws + alloc((size_t)1536 * KPAD_G * 2));      // W1^T ++ Wm1^T ++ zeros
    unsigned short* w2t    = (unsigned short*)(ws + alloc((size_t)F1 * F1 * 2));
    unsigned short* wm2t   = (unsigned short*)(ws + alloc((size_t)128 * 128 * 2));
    unsigned short* t_bf   = (unsigned short*)(ws + alloc((size_t)M_PAD * 128 * 2));
    float*  alpha  = (float*) (ws + alloc((size_t)2 * E_TOT * HEADS * 4));
    float2* minv   = (float2*)(ws + alloc((size_t)2 * N_NODESC * HEADS * 8));
    float*  es     = (float*) (ws + alloc((size_t)2 * N_NODESC * HEADS * 4));
    float*  edv    = (float*) (ws + alloc((size_t)2 * N_NODESC * HEADS * 4));
    int*    cnt    = (int*)   (ws + alloc((size_t)N_NODESC * 4));
    int*    rowp   = (int*)   (ws + alloc((size_t)(N_NODESC + 16) * 4));
    int*    cursor = (int*)   (ws + alloc((size_t)N_NODESC * 4));
    int*    colsrc = (int*)   (ws + alloc((size_t)E_TOT * 4));
    int*    dstof  = (int*)   (ws + alloc((size_t)E_TOT * 4));
    float*  gx01   = (float*) (ws + alloc((size_t)2 * M_PAD * 128 * 4));
    float*  gx2    = (float*) (ws + alloc((size_t)M_PAD * 128 * 4));
    float*  gsum   = (float*) (ws + alloc((size_t)384 * 4));
    unsigned short* h1x2 = xbuf2;        // alias: xbuf2 dead after L1 GEMM
    unsigned short* tmp2 = xbuf2;        // alias: h1x2 dead after L2 GEMM
    (void)ws_size; (void)in_sizes; (void)n_in; (void)out_size;

    hipMemsetAsync(cnt, 0, (size_t)N_NODESC * 4, stream);
    hipMemsetAsync(gsum, 0, 384 * 4, stream);
    hipMemsetAsync(w1t + (size_t)1408 * KPAD_G, 0, (size_t)128 * KPAD_G * 2, stream);  // zero-pad B rows

    // fused: convert_both + 4 transposes + hist
    prologue_k<<<PROLOGUE_BLOCKS, 256, 0, stream>>>(x, noise, xbuf2, W1, Wm1, W2, Wm2,
                                                    w1t, w2t, wm2t, ei, cnt);
    scan_k   <<<1, 1024, 0, stream>>>(cnt, rowp, cursor);
    scatter_k<<<(E_TOT + 255) / 256, 256, 0, stream>>>(ei, cursor, colsrc, dstof);

    // ---- L1 GEMM with folded MLP layer 1 (N = 1536 = 6 tiles) ----
    gemm256<0,1><<<RT_TILES * 6, 512, 0, stream>>>(xbuf2, KPAD_G, w1t, KPAD_G,
        hraw2, F1, 32, 6, N_NODESC, bm1, t_bf);
    // MLP layer 2 (reads t_bf produced above)
    gemm2<1,1,0><<<RT_TILES, 256, 0, stream>>>(t_bf, 128, wm2t, 128,
        bm2, gx2, 128, 4, 1, N_NODESC);

    escores2_k<<<N_NODESC, 320, 0, stream>>>(hraw2, a1s, a1d, es, edv);
    alpha_k <<<(2 * E_TOT + 255) / 256, 256, 0, stream>>>(colsrc, dstof, es, edv, alpha);
    nodems_k<<<(2 * N_NODESC * HEADS + 255) / 256, 256, 0, stream>>>(rowp, alpha, minv);
    wexp_k  <<<(2 * E_TOT + 255) / 256, 256, 0, stream>>>(dstof, minv, alpha);
    agg_slice_k<1><<<12500, 256, 0, stream>>>(rowp, colsrc, alpha, hraw2, b1, h1x2);

    gemm256<0,0><<<RT_TILES * 5, 512, 0, stream>>>(h1x2, F1, w2t, F1,
        hraw2, F1, 20, 5, N_NODESC, nullptr, nullptr);
    escores2_k<<<N_NODESC, 320, 0, stream>>>(hraw2, a2s, a2d, es, edv);
    alpha_k <<<(2 * E_TOT + 255) / 256, 256, 0, stream>>>(colsrc, dstof, es, edv, alpha);
    nodems_k<<<(2 * N_NODESC * HEADS + 255) / 256, 256, 0, stream>>>(rowp, alpha, minv);
    wexp_k  <<<(2 * E_TOT + 255) / 256, 256, 0, stream>>>(dstof, minv, alpha);
    agg_slice_k<0><<<12500, 256, 0, stream>>>(rowp, colsrc, alpha, hraw2, nullptr, tmp2);
    headmean_k<<<1250, 256, 0, stream>>>(tmp2, b2, gx01);

    projsum_k<<<7620, 256, 0, stream>>>(gx01, gx2, Wf, bfv, Wc, bc, out, gsum);
    loss_k  <<<1, 128, 0, stream>>>(gsum, out + 1920000);
}

// Round 14
// 567.688 us; speedup vs baseline: 1.1982x; 1.0282x over previous
//
#include <hip/hip_runtime.h>
#include <hip/hip_bf16.h>

// ---------------- problem constants ----------------
#define N_NODESC 10000
#define M_PAD    10112          // 79 * 128
#define RT_TILES 79
#define NUM_GENE 2000
#define KPAD_G   2048
#define N_EDGESC 160000
#define E_TOT    170000         // + self loops
#define HEADS    10
#define F1       1280           // HEADS*128
#define LATENTC  128
#define LOWERC   64
#define CLUST    15

typedef __attribute__((ext_vector_type(8))) short   short8;
typedef __attribute__((ext_vector_type(4))) float   f32x4;
typedef __attribute__((ext_vector_type(4))) unsigned short ushort4_;

__device__ __forceinline__ float bf2f(unsigned short u){
    unsigned int x = ((unsigned int)u) << 16;
    return __builtin_bit_cast(float, x);
}
__device__ __forceinline__ unsigned short f2bf(float f){
    __hip_bfloat16 h = __float2bfloat16(f);
    return __builtin_bit_cast(unsigned short, h);
}
__device__ __forceinline__ void gload16(const void* g, void* l) {
    __builtin_amdgcn_global_load_lds((const __attribute__((address_space(1))) void*)g,
                                     (__attribute__((address_space(3))) void*)l, 16, 0, 0);
}

// ======== 256x256 bf16 MFMA GEMM — 4-phase quadrant schedule, counted vmcnt ========
// (FROZEN: R12's proven best schedule.)
template<int OMODE, int FOLD>   // OMODE: 0 bf16 out, 1 f32 out
__global__ __launch_bounds__(512, 2)
void gemm256(const unsigned short* __restrict__ A, int lda,
             const unsigned short* __restrict__ BT, int ldb,
             void* __restrict__ Cp, int ldc,
             int NK, int NT, int M_real,
             const float* __restrict__ mbias, unsigned short* __restrict__ mout)
{
    __shared__ short smem[65536];   // 128 KiB

    const int nwg = gridDim.x;
    const int q = nwg >> 3, r = nwg & 7;
    const int xcd = blockIdx.x & 7, idx = blockIdx.x >> 3;
    const int wgid = (xcd < r ? xcd * (q + 1) : r * (q + 1) + (xcd - r) * q) + idx;
    const int bm = wgid / NT, bn = wgid - bm * NT;

    const int t = threadIdx.x, w = t >> 6, lane = t & 63;
    const int wr2 = (w >> 2) * 64;
    const int wc2 = (w & 3) * 32;
    const int lrow = lane & 15, lq = lane >> 4;

    int rowc[2], swc[2], loff[2];
    #pragma unroll
    for (int cc = 0; cc < 2; ++cc) {
        int c = cc * 512 + t;
        int row = c >> 3, slot = c & 7;
        rowc[cc] = row;
        swc[cc]  = (slot ^ (row & 7)) << 3;
        loff[cc] = c * 8;
    }
    auto stageA = [&](int buf, int h, int kt) {
        short* dst = smem + buf * 32768 + h * 8192;
        const unsigned short* src = A + (size_t)(bm * 256 + h * 128) * lda + kt * 64;
        #pragma unroll
        for (int cc = 0; cc < 2; ++cc)
            gload16(src + (size_t)rowc[cc] * lda + swc[cc], dst + loff[cc]);
    };
    auto stageB = [&](int buf, int h, int kt) {
        short* dst = smem + buf * 32768 + 16384 + h * 8192;
        const unsigned short* src = BT + (size_t)(bn * 256 + h * 128) * ldb + kt * 64;
        #pragma unroll
        for (int cc = 0; cc < 2; ++cc)
            gload16(src + (size_t)rowc[cc] * ldb + swc[cc], dst + loff[cc]);
    };
    auto rdA = [&](int buf, int h, int mi, int ks) -> short8 {
        int r7 = wr2 + mi * 16 + lrow;
        return *(const short8*)(smem + buf * 32768 + h * 8192 + r7 * 64
                                + (((ks * 4 + lq) ^ (r7 & 7)) << 3));
    };
    auto rdB = [&](int buf, int h, int ni, int ks) -> short8 {
        int r7 = wc2 + ni * 16 + lrow;
        return *(const short8*)(smem + buf * 32768 + 16384 + h * 8192 + r7 * 64
                                + (((ks * 4 + lq) ^ (r7 & 7)) << 3));
    };

    f32x4 acc00[4][2] = {}, acc01[4][2] = {}, acc10[4][2] = {}, acc11[4][2] = {};
    short8 a0[4][2], a1[4][2], b0[2][2], b1[2][2];

    auto domfma = [&](f32x4 (&ac)[4][2], short8 (&aa)[4][2], short8 (&bb)[2][2]) {
        __builtin_amdgcn_s_setprio(1);
        #pragma unroll
        for (int mi = 0; mi < 4; ++mi)
            #pragma unroll
            for (int ni = 0; ni < 2; ++ni)
                #pragma unroll
                for (int ks = 0; ks < 2; ++ks)
                    ac[mi][ni] = __builtin_amdgcn_mfma_f32_16x16x32_bf16(
                        aa[mi][ks], bb[ni][ks], ac[mi][ni], 0, 0, 0);
        __builtin_amdgcn_s_setprio(0);
    };

    stageA(0, 0, 0); stageB(0, 0, 0); stageB(0, 1, 0); stageA(0, 1, 0);

    for (int kt = 0; kt < NK; ++kt) {
        const int buf = kt & 1, nbuf = buf ^ 1;
        const bool pf = (kt + 1 < NK);
        asm volatile("s_waitcnt vmcnt(4)" ::: "memory");
        __builtin_amdgcn_sched_barrier(0);
        __builtin_amdgcn_s_barrier();
        __builtin_amdgcn_sched_barrier(0);
        #pragma unroll
        for (int mi = 0; mi < 4; ++mi) { a0[mi][0] = rdA(buf, 0, mi, 0); a0[mi][1] = rdA(buf, 0, mi, 1); }
        #pragma unroll
        for (int ni = 0; ni < 2; ++ni) { b0[ni][0] = rdB(buf, 0, ni, 0); b0[ni][1] = rdB(buf, 0, ni, 1); }
        if (pf) { stageA(nbuf, 0, kt + 1); stageB(nbuf, 0, kt + 1); }
        domfma(acc00, a0, b0);
        if (pf) { asm volatile("s_waitcnt vmcnt(4)" ::: "memory"); }
        else    { asm volatile("s_waitcnt vmcnt(0)" ::: "memory"); }
        __builtin_amdgcn_sched_barrier(0);
        __builtin_amdgcn_s_barrier();
        __builtin_amdgcn_sched_barrier(0);
        #pragma unroll
        for (int ni = 0; ni < 2; ++ni) { b1[ni][0] = rdB(buf, 1, ni, 0); b1[ni][1] = rdB(buf, 1, ni, 1); }
        if (pf) stageB(nbuf, 1, kt + 1);
        domfma(acc01, a0, b1);
        #pragma unroll
        for (int mi = 0; mi < 4; ++mi) { a1[mi][0] = rdA(buf, 1, mi, 0); a1[mi][1] = rdA(buf, 1, mi, 1); }
        if (pf) stageA(nbuf, 1, kt + 1);
        domfma(acc10, a1, b0);
        domfma(acc11, a1, b1);
    }

    const bool mlp_tile = FOLD && (bn == NT - 1);
    #pragma unroll
    for (int qa = 0; qa < 2; ++qa) {
        #pragma unroll
        for (int qb = 0; qb < 2; ++qb) {
            f32x4 (&ac)[4][2] = (qa == 0) ? (qb == 0 ? acc00 : acc01)
                                          : (qb == 0 ? acc10 : acc11);
            if (mlp_tile) {
                if (qb != 0) continue;
                #pragma unroll
                for (int mi = 0; mi < 4; ++mi) {
                    #pragma unroll
                    for (int ni = 0; ni < 2; ++ni) {
                        int col = wc2 + ni * 16 + lrow;
                        #pragma unroll
                        for (int qq = 0; qq < 4; ++qq) {
                            int grow = bm * 256 + qa * 128 + wr2 + mi * 16 + lq * 4 + qq;
                            if (grow < N_NODESC) {
                                float val = fmaxf(ac[mi][ni][qq] + mbias[col], 0.f);
                                mout[(size_t)grow * 128 + col] = f2bf(val);
                            }
                        }
                    }
                }
                continue;
            }
            #pragma unroll
            for (int mi = 0; mi < 4; ++mi) {
                #pragma unroll
                for (int ni = 0; ni < 2; ++ni) {
                    int gcol = bn * 256 + qb * 128 + wc2 + ni * 16 + lrow;
                    #pragma unroll
                    for (int qq = 0; qq < 4; ++qq) {
                        int grow = bm * 256 + qa * 128 + wr2 + mi * 16 + lq * 4 + qq;
                        float val = ac[mi][ni][qq];
                        int rslab = grow >= M_PAD ? grow - M_PAD : grow;
                        if (rslab >= M_real) val = 0.f;
                        if constexpr (OMODE == 0)
                            ((unsigned short*)Cp)[(size_t)grow * ldc + gcol] = f2bf(val);
                        else
                            ((float*)Cp)[(size_t)grow * ldc + gcol] = val;
                    }
                }
            }
        }
    }
}

// ---------------- 128x128 bf16 GEMM (MLP2), dbuf 2-phase ----------------
template<int OMODE, int BIAS, int RELU>
__global__ __launch_bounds__(256)
void gemm2(const unsigned short* __restrict__ A, int lda,
           const unsigned short* __restrict__ BT, int ldb,
           const float* __restrict__ bias,
           void* __restrict__ Cp, int ldc,
           int KT, int NT, int M_real)
{
    __shared__ short smem[16384];

    const int nwg = gridDim.x;
    const int q = nwg >> 3, r = nwg & 7;
    const int xcd = blockIdx.x & 7, idx = blockIdx.x >> 3;
    const int wgid = (xcd < r ? xcd * (q + 1) : r * (q + 1) + (xcd - r) * q) + idx;
    const int bm = wgid / NT, bn = wgid - bm * NT;

    const int t = threadIdx.x, w = t >> 6, lane = t & 63;
    const int wr = (w >> 1) * 64, wc = (w & 1) * 64;
    const int lrow = lane & 15, lq = lane >> 4;

    const unsigned short* Ag[2];
    const unsigned short* Bg[2];
    int lds_off[2];
    #pragma unroll
    for (int cc = 0; cc < 2; ++cc) {
        int c = cc * 256 + t;
        int row = c >> 2, slot = c & 3;
        int gk = (slot ^ ((row >> 1) & 3)) << 3;
        Ag[cc] = A  + (size_t)(bm * 128 + row) * lda + gk;
        Bg[cc] = BT + (size_t)(bn * 128 + row) * ldb + gk;
        lds_off[cc] = cc * 2048 + w * 512 + lane * 8;
    }

    auto stage = [&](int buf, int kt) {
        const int kk = kt * 32;
        #pragma unroll
        for (int cc = 0; cc < 2; ++cc) {
            gload16(Ag[cc] + kk, smem + buf * 8192 + lds_off[cc]);
            gload16(Bg[cc] + kk, smem + buf * 8192 + 4096 + lds_off[cc]);
        }
    };

    f32x4 acc[4][4] = {};
    stage(0, 0);
    __syncthreads();
    int cur = 0;
    for (int kt = 0; kt < KT; ++kt) {
        if (kt + 1 < KT) stage(cur ^ 1, kt + 1);
        const short* As = smem + cur * 8192;
        const short* Bs = As + 4096;
        short8 af[4], bf_[4];
        #pragma unroll
        for (int mi = 0; mi < 4; ++mi) {
            int rr = wr + mi * 16 + lrow;
            af[mi] = *(const short8*)(&As[rr * 32 + ((lq ^ ((rr >> 1) & 3)) << 3)]);
        }
        #pragma unroll
        for (int ni = 0; ni < 4; ++ni) {
            int rr = wc + ni * 16 + lrow;
            bf_[ni] = *(const short8*)(&Bs[rr * 32 + ((lq ^ ((rr >> 1) & 3)) << 3)]);
        }
        #pragma unroll
        for (int mi = 0; mi < 4; ++mi)
            #pragma unroll
            for (int ni = 0; ni < 4; ++ni)
                acc[mi][ni] = __builtin_amdgcn_mfma_f32_16x16x32_bf16(af[mi], bf_[ni], acc[mi][ni], 0, 0, 0);
        __syncthreads();
        cur ^= 1;
    }

    #pragma unroll
    for (int mi = 0; mi < 4; ++mi) {
        #pragma unroll
        for (int ni = 0; ni < 4; ++ni) {
            int gcol = bn * 128 + wc + ni * 16 + lrow;
            #pragma unroll
            for (int qq = 0; qq < 4; ++qq) {
                int grow = bm * 128 + wr + mi * 16 + lq * 4 + qq;
                float val = acc[mi][ni][qq];
                if constexpr (BIAS) val += bias[gcol];
                if constexpr (RELU) val = fmaxf(val, 0.f);
                if (grow >= M_real) val = 0.f;
                ((float*)Cp)[(size_t)grow * ldc + gcol] = val;
            }
        }
    }
}

// ---------------- fused prologue: convert_both + 4 transposes + hist ----------------
__device__ __forceinline__ void convert_body(const float* __restrict__ x,
                                             const float* __restrict__ noise,
                                             unsigned short* __restrict__ out, int row)
{
    __shared__ float sred[4];
    __shared__ float srn;
    int t = threadIdx.x;
    int kc = t * 8;
    f32x4 n0 = {}, n1 = {};
    float ss = 0.f;
    if (t < 250) {
        n0 = *(const f32x4*)(noise + (size_t)row * NUM_GENE + kc);
        n1 = *(const f32x4*)(noise + (size_t)row * NUM_GENE + kc + 4);
        ss = n0.x*n0.x + n0.y*n0.y + n0.z*n0.z + n0.w*n0.w
           + n1.x*n1.x + n1.y*n1.y + n1.z*n1.z + n1.w*n1.w;
    }
    for (int off = 32; off; off >>= 1) ss += __shfl_down(ss, off);
    if ((t & 63) == 0) sred[t >> 6] = ss;
    __syncthreads();
    if (t == 0) srn = 1.f / fmaxf(sqrtf(sred[0] + sred[1] + sred[2] + sred[3]), 1e-12f);
    __syncthreads();
    if (t >= 250) return;
    float rn = srn;
    f32x4 a0 = *(const f32x4*)(x + (size_t)row * NUM_GENE + kc);
    f32x4 a1 = *(const f32x4*)(x + (size_t)row * NUM_GENE + kc + 4);
    short8 v0, v1;
    #pragma unroll
    for (int i = 0; i < 4; ++i) {
        v0[i]     = (short)f2bf(a0[i]);
        v0[4 + i] = (short)f2bf(a1[i]);
        v1[i]     = (short)f2bf(a0[i] + n0[i] * rn);
        v1[4 + i] = (short)f2bf(a1[i] + n1[i] * rn);
    }
    *(short8*)(out + (size_t)row * KPAD_G + kc) = v0;
    *(short8*)(out + (size_t)(M_PAD + row) * KPAD_G + kc) = v1;
}

__device__ __forceinline__ void transpose_body(const float* __restrict__ in,
                                               unsigned short* __restrict__ out,
                                               int R, int C, int Kpad, int bx, int by)
{
    __shared__ float tile[32][33];
    int tx = threadIdx.x & 31, ty = threadIdx.x >> 5;
    int c0 = bx * 32, r0 = by * 32;
    #pragma unroll
    for (int i = 0; i < 4; ++i) {
        int r = r0 + ty + i * 8, c = c0 + tx;
        tile[ty + i * 8][tx] = (r < R && c < C) ? in[(size_t)r * C + c] : 0.f;
    }
    __syncthreads();
    #pragma unroll
    for (int i = 0; i < 4; ++i) {
        int c = c0 + ty + i * 8;
        int r = r0 + tx;
        if (c < C && r < Kpad) out[(size_t)c * Kpad + r] = f2bf(tile[tx][ty + i * 8]);
    }
}

__global__ void prologue_k(const float* __restrict__ x, const float* __restrict__ noise,
                           unsigned short* __restrict__ xbuf,
                           const float* __restrict__ W1, const float* __restrict__ Wm1,
                           const float* __restrict__ W2, const float* __restrict__ Wm2,
                           unsigned short* __restrict__ w1t, unsigned short* __restrict__ w2t,
                           unsigned short* __restrict__ wm2t,
                           const int* __restrict__ ei, int* __restrict__ cnt)
{
    int b = blockIdx.x;
    if (b < 10000) { convert_body(x, noise, xbuf, b); return; }
    b -= 10000;
    if (b < 2560) { transpose_body(W1, w1t, NUM_GENE, F1, KPAD_G, b % 40, b / 40); return; }
    b -= 2560;
    if (b < 256)  { transpose_body(Wm1, w1t + (size_t)1280 * KPAD_G, NUM_GENE, 128, KPAD_G, b % 4, b / 4); return; }
    b -= 256;
    if (b < 1600) { transpose_body(W2, w2t, F1, F1, F1, b % 40, b / 40); return; }
    b -= 1600;
    if (b < 16)   { transpose_body(Wm2, wm2t, 128, 128, 128, b % 4, b / 4); return; }
    b -= 16;
    int e = b * 256 + threadIdx.x;
    if (e < E_TOT) {
        int d = (e < N_EDGESC) ? ei[N_EDGESC + e] : (e - N_EDGESC);
        atomicAdd(&cnt[d], 1);
    }
}
#define PROLOGUE_BLOCKS (10000 + 2560 + 256 + 1600 + 16 + 665)

// ---------------- CSR scan + scatter ----------------
__global__ void scan_k(const int* __restrict__ cnt, int* __restrict__ rowp, int* __restrict__ cursor)
{
    __shared__ int buf[1024];
    int t = threadIdx.x;
    int loc[10];
    int s = 0, base = t * 10;
    #pragma unroll
    for (int i = 0; i < 10; ++i) {
        int idx = base + i;
        int v = (idx < N_NODESC) ? cnt[idx] : 0;
        loc[i] = v; s += v;
    }
    buf[t] = s; __syncthreads();
    for (int off = 1; off < 1024; off <<= 1) {
        int tmp = (t >= off) ? buf[t - off] : 0;
        __syncthreads();
        buf[t] += tmp;
        __syncthreads();
    }
    int run = buf[t] - s;
    #pragma unroll
    for (int i = 0; i < 10; ++i) {
        int idx = base + i;
        if (idx < N_NODESC) { rowp[idx] = run; cursor[idx] = run; run += loc[i]; }
    }
    if (t == 1023) rowp[N_NODESC] = buf[1023];
}

__global__ void scatter_k(const int* __restrict__ ei, int* __restrict__ cursor,
                          int* __restrict__ col_src, int* __restrict__ dst_of)
{
    int e = blockIdx.x * 256 + threadIdx.x;
    if (e >= E_TOT) return;
    int s, d;
    if (e < N_EDGESC) { s = ei[e]; d = ei[N_EDGESC + e]; } else { s = d = e - N_EDGESC; }
    int pos = atomicAdd(&cursor[d], 1);
    col_src[pos] = s;
    dst_of[pos] = d;
}

// ---------------- attention scores for both passes; 320 thr = 2 nodes ----------------
__global__ void escores2_k(const unsigned short* __restrict__ h,
                           const float* __restrict__ a_src, const float* __restrict__ a_dst,
                           float* __restrict__ e_s, float* __restrict__ e_d)
{
    int t = threadIdx.x;
    int half = (t >= 160);
    int tl = t - half * 160;
    int node2 = blockIdx.x * 2 + half;
    int p = node2 >= N_NODESC;
    int n = node2 - p * N_NODESC;
    int hh = tl >> 4, c = tl & 15;
    int off = hh * 128 + c * 8;
    short8 v = *(const short8*)(h + (size_t)(p * M_PAD + n) * F1 + off);
    float ps = 0.f, pd = 0.f;
    #pragma unroll
    for (int j = 0; j < 8; ++j) {
        float f = bf2f((unsigned short)v[j]);
        ps += f * a_src[off + j];
        pd += f * a_dst[off + j];
    }
    #pragma unroll
    for (int m = 1; m < 16; m <<= 1) {
        ps += __shfl_xor(ps, m, 16);
        pd += __shfl_xor(pd, m, 16);
    }
    if (c == 0) { e_s[node2 * HEADS + hh] = ps; e_d[node2 * HEADS + hh] = pd; }
}

// ---------------- per-edge alpha -> TRANSPOSED layout [pass][head][E] ----------------
__global__ void alpha_k(const int* __restrict__ colsrc, const int* __restrict__ dstof,
                        const float* __restrict__ e_s, const float* __restrict__ e_d,
                        float* __restrict__ alpha)
{
    int gid = blockIdx.x * 256 + threadIdx.x;
    if (gid >= 2 * E_TOT) return;
    int p = gid >= E_TOT;
    int e = gid - p * E_TOT;
    int s = colsrc[e], d = dstof[e];
    const float* er = e_s + (size_t)(p * N_NODESC + s) * HEADS;
    const float* dr = e_d + (size_t)(p * N_NODESC + d) * HEADS;
    #pragma unroll
    for (int h = 0; h < HEADS; ++h) {
        float a = er[h] + dr[h];
        a = a >= 0.f ? a : 0.2f * a;
        alpha[((size_t)p * HEADS + h) * E_TOT + e] = a;
    }
}

// ---------------- per-(pass,node,head) online max/sum ----------------
__global__ void nodems_k(const int* __restrict__ rowp, const float* __restrict__ alpha,
                         float2* __restrict__ minv)
{
    int gid = blockIdx.x * 256 + threadIdx.x;
    if (gid >= 2 * N_NODESC * HEADS) return;
    int p = gid >= N_NODESC * HEADS;
    int rr = gid - p * N_NODESC * HEADS;
    int n = rr / HEADS, hh = rr - n * HEADS;
    int beg = rowp[n], end = rowp[n + 1];
    const float* ap = alpha + ((size_t)p * HEADS + hh) * E_TOT;
    float m = -1e30f, ssum = 0.f;
    for (int e = beg; e < end; ++e) {
        float a = ap[e];
        if (a > m) { ssum = ssum * __expf(m - a) + 1.f; m = a; }
        else ssum += __expf(a - m);
    }
    float2 qo; qo.x = m; qo.y = 1.f / ssum;
    minv[gid] = qo;
}

// ---------------- sliced aggregation, XCD-chunked, softmax weight computed inline ----
// edges of node n all have dst == n, so w[e] = exp(alpha_raw[e] - m[n,s]) * inv[n,s]
// with (m,inv) loaded once per thread. Replaces the wexp_k pass entirely.
template<int L1MODE>
__global__ void agg_slice_k(const int* __restrict__ rowp, const int* __restrict__ colsrc,
                            const float* __restrict__ alpha, const float2* __restrict__ minv,
                            const unsigned short* __restrict__ h,
                            const float* __restrict__ bias,
                            unsigned short* __restrict__ out)
{
    const int nwg = gridDim.x;             // 12500
    const int q = nwg >> 3, r = nwg & 7;
    const int xcd = blockIdx.x & 7, idx = blockIdx.x >> 3;
    const int wgid = (xcd < r ? xcd * (q + 1) : r * (q + 1) + (xcd - r) * q) + idx;
    int ps = wgid / 625, nb = wgid - ps * 625;
    int p = ps / HEADS, s = ps - p * HEADS;
    int t = threadIdx.x;
    int nl = t >> 4, l16 = t & 15;
    int n = nb * 16 + nl;
    int beg = rowp[n], end = rowp[n + 1];
    const unsigned short* hb = h + (size_t)p * M_PAD * F1 + s * 128 + l16 * 8;
    const float* wb = alpha + ((size_t)p * HEADS + s) * E_TOT;
    const float2 mv = minv[((size_t)p * N_NODESC + n) * HEADS + s];
    float acc[8] = {};
    int e = beg;
    if (e < end) {
        float av = wb[e];
        short8 rv = *(const short8*)(hb + (size_t)colsrc[e] * F1);
        for (++e; e < end; ++e) {
            float av2 = wb[e];
            short8 rv2 = *(const short8*)(hb + (size_t)colsrc[e] * F1);
            float wv = __expf(av - mv.x) * mv.y;
            #pragma unroll
            for (int j = 0; j < 8; ++j) acc[j] += wv * bf2f((unsigned short)rv[j]);
            av = av2; rv = rv2;
        }
        float wv = __expf(av - mv.x) * mv.y;
        #pragma unroll
        for (int j = 0; j < 8; ++j) acc[j] += wv * bf2f((unsigned short)rv[j]);
    }
    short8 o;
    if constexpr (L1MODE) {
        #pragma unroll
        for (int j = 0; j < 8; ++j)
            o[j] = (short)f2bf(fmaxf(acc[j] + bias[s * 128 + l16 * 8 + j], 0.f));
    } else {
        #pragma unroll
        for (int j = 0; j < 8; ++j) o[j] = (short)f2bf(acc[j]);
    }
    *(short8*)(out + (size_t)(p * M_PAD + n) * F1 + s * 128 + l16 * 8) = o;
}

// ---------------- head-mean + bias + relu ----------------
__global__ void headmean_k(const unsigned short* __restrict__ tmp, const float* __restrict__ b2,
                           float* __restrict__ out)
{
    int gid = blockIdx.x * 256 + threadIdx.x;
    int pn = gid >> 4, d8 = (gid & 15) * 8;
    int p = pn >= N_NODESC;
    int n = pn - p * N_NODESC;
    const unsigned short* tp = tmp + (size_t)(p * M_PAD + n) * F1 + d8;
    float acc[8] = {};
    #pragma unroll
    for (int hh = 0; hh < HEADS; ++hh) {
        short8 v = *(const short8*)(tp + hh * 128);
        #pragma unroll
        for (int j = 0; j < 8; ++j) acc[j] += bf2f((unsigned short)v[j]);
    }
    float* op = out + (size_t)(p * M_PAD + n) * LATENTC + d8;
    #pragma unroll
    for (int j = 0; j < 8; ++j) op[j] = fmaxf(acc[j] * 0.1f + b2[d8 + j], 0.f);
}

// ---------------- fused projection heads + column sums ----------------
__global__ void projsum_k(const float* __restrict__ g01, const float* __restrict__ g2,
                          const float* __restrict__ Wf, const float* __restrict__ bfv,
                          const float* __restrict__ Wc, const float* __restrict__ bc,
                          float* __restrict__ out, float* __restrict__ gsum)
{
    int b = blockIdx.x;
    if (b < 7500) {
        __shared__ float rowb[4][128];
        int m = b / 2500, bx = b - m * 2500;
        const float* gx = (m == 0) ? g01 : (m == 1) ? g01 + (size_t)M_PAD * 128 : g2;
        float* out_node = out + (size_t)m * 640000;
        float* out_c = (m == 0) ? out + 1920001 : (m == 1) ? out + 2070001 : nullptr;
        int wid = threadIdx.x >> 6, l = threadIdx.x & 63;
        int n = bx * 4 + wid;
        if (n >= N_NODESC) return;
        rowb[wid][l]      = gx[(size_t)n * 128 + l];
        rowb[wid][l + 64] = gx[(size_t)n * 128 + 64 + l];
        float acc = bfv[l];
        #pragma unroll 8
        for (int k = 0; k < 128; ++k) acc += rowb[wid][k] * Wf[k * 64 + l];
        out_node[(size_t)n * 64 + l] = acc;
        if (out_c != nullptr && l < CLUST) {
            float a2 = bc[l];
            #pragma unroll 8
            for (int k = 0; k < 128; ++k) a2 += rowb[wid][k] * Wc[k * CLUST + l];
            out_c[(size_t)l * N_NODESC + n] = a2;
        }
        return;
    }
    b -= 7500;                              // colsum: 120 blocks
    int v = b / 40, bb = b % 40;
    const float* src = (v == 0) ? g01 : (v == 1) ? g01 + (size_t)M_PAD * 128 : g2;
    int t = threadIdx.x, col = t & 127, ro = t >> 7;
    int rend = min((bb + 1) * 250, N_NODESC);
    float acc = 0.f;
    for (int rr = bb * 250 + ro; rr < rend; rr += 2) acc += src[(size_t)rr * 128 + col];
    __shared__ float part[256];
    part[t] = acc; __syncthreads();
    if (t < 128) atomicAdd(&gsum[v * 128 + col], part[t] + part[t + 128]);
}

// ---------------- contrastive loss scalar ----------------
__global__ void loss_k(const float* __restrict__ gsum, float* __restrict__ out)
{
    int t = threadIdx.x;   // 128
    float g0 = gsum[t] * 1e-4f, g1 = gsum[128 + t] * 1e-4f, g2 = gsum[256 + t] * 1e-4f;
    float d01 = g0 * g1, d02 = g0 * g2, d12 = g1 * g2;
    for (int off = 32; off; off >>= 1) {
        d01 += __shfl_down(d01, off); d02 += __shfl_down(d02, off); d12 += __shfl_down(d12, off);
    }
    __shared__ float s[3][2];
    if ((t & 63) == 0) { int w = t >> 6; s[0][w] = d01; s[1][w] = d02; s[2][w] = d12; }
    __syncthreads();
    if (t == 0) {
        float a01 = (s[0][0] + s[0][1]) * 5.f;
        float a02 = (s[1][0] + s[1][1]) * 5.f;
        float a12 = (s[2][0] + s[2][1]) * 5.f;
        float m = fmaxf(a01, fmaxf(a02, a12));
        float se = expf(a01 - m) + expf(a02 - m) + expf(a12 - m);
        *out = -((a01 - m) - logf(se)) / 2.302585092994046f;
    }
}

// ---------------- host ----------------
extern "C" void kernel_launch(void* const* d_in, const int* in_sizes, int n_in,
                              void* d_out, int out_size, void* d_ws, size_t ws_size,
                              hipStream_t stream)
{
    const float* x     = (const float*)d_in[0];
    const int*   ei    = (const int*)  d_in[1];
    const float* noise = (const float*)d_in[2];
    const float* W1    = (const float*)d_in[3];
    const float* a1s   = (const float*)d_in[4];
    const float* a1d   = (const float*)d_in[5];
    const float* b1    = (const float*)d_in[6];
    const float* W2    = (const float*)d_in[7];
    const float* a2s   = (const float*)d_in[8];
    const float* a2d   = (const float*)d_in[9];
    const float* b2    = (const float*)d_in[10];
    const float* Wm1   = (const float*)d_in[11];
    const float* bm1   = (const float*)d_in[12];
    const float* Wm2   = (const float*)d_in[13];
    const float* bm2   = (const float*)d_in[14];
    const float* Wf    = (const float*)d_in[15];
    const float* bfv   = (const float*)d_in[16];
    const float* Wc    = (const float*)d_in[17];
    const float* bc    = (const float*)d_in[18];
    float* out = (float*)d_out;

    size_t off = 0;
    auto alloc = [&](size_t bytes) { size_t o = off; off = (off + bytes + 255) & ~(size_t)255; return o; };
    char* ws = (char*)d_ws;
    unsigned short* xbuf2  = (unsigned short*)(ws + alloc((size_t)2 * M_PAD * KPAD_G * 2)); // later h1x2 / agg2 tmp
    unsigned short* hraw2  = (unsigned short*)(ws + alloc((size_t)2 * M_PAD * F1 * 2));
    unsigned short* w1t    = (unsigned short*)(ws + alloc((size_t)1536 * KPAD_G * 2));      // W1^T ++ Wm1^T ++ zeros
    unsigned short* w2t    = (unsigned short*)(ws + alloc((size_t)F1 * F1 * 2));
    unsigned short* wm2t   = (unsigned short*)(ws + alloc((size_t)128 * 128 * 2));
    unsigned short* t_bf   = (unsigned short*)(ws + alloc((size_t)M_PAD * 128 * 2));
    float*  alpha  = (float*) (ws + alloc((size_t)2 * E_TOT * HEADS * 4));
    float2* minv   = (float2*)(ws + alloc((size_t)2 * N_NODESC * HEADS * 8));
    float*  es     = (float*) (ws + alloc((size_t)2 * N_NODESC * HEADS * 4));
    float*  edv    = (float*) (ws + alloc((size_t)2 * N_NODESC * HEADS * 4));
    int*    cnt    = (int*)   (ws + alloc((size_t)N_NODESC * 4));
    int*    rowp   = (int*)   (ws + alloc((size_t)(N_NODESC + 16) * 4));
    int*    cursor = (int*)   (ws + alloc((size_t)N_NODESC * 4));
    int*    colsrc = (int*)   (ws + alloc((size_t)E_TOT * 4));
    int*    dstof  = (int*)   (ws + alloc((size_t)E_TOT * 4));
    float*  gx01   = (float*) (ws + alloc((size_t)2 * M_PAD * 128 * 4));
    float*  gx2    = (float*) (ws + alloc((size_t)M_PAD * 128 * 4));
    float*  gsum   = (float*) (ws + alloc((size_t)384 * 4));
    unsigned short* h1x2 = xbuf2;        // alias: xbuf2 dead after L1 GEMM
    unsigned short* tmp2 = xbuf2;        // alias: h1x2 dead after L2 GEMM
    (void)ws_size; (void)in_sizes; (void)n_in; (void)out_size;

    hipMemsetAsync(cnt, 0, (size_t)N_NODESC * 4, stream);
    hipMemsetAsync(gsum, 0, 384 * 4, stream);
    hipMemsetAsync(w1t + (size_t)1408 * KPAD_G, 0, (size_t)128 * KPAD_G * 2, stream);  // zero-pad B rows

    // fused: convert_both + 4 transposes + hist
    prologue_k<<<PROLOGUE_BLOCKS, 256, 0, stream>>>(x, noise, xbuf2, W1, Wm1, W2, Wm2,
                                                    w1t, w2t, wm2t, ei, cnt);
    scan_k   <<<1, 1024, 0, stream>>>(cnt, rowp, cursor);
    scatter_k<<<(E_TOT + 255) / 256, 256, 0, stream>>>(ei, cursor, colsrc, dstof);

    // ---- L1 GEMM with folded MLP layer 1 (N = 1536 = 6 tiles) ----
    gemm256<0,1><<<RT_TILES * 6, 512, 0, stream>>>(xbuf2, KPAD_G, w1t, KPAD_G,
        hraw2, F1, 32, 6, N_NODESC, bm1, t_bf);
    // MLP layer 2 (reads t_bf produced above)
    gemm2<1,1,0><<<RT_TILES, 256, 0, stream>>>(t_bf, 128, wm2t, 128,
        bm2, gx2, 128, 4, 1, N_NODESC);

    escores2_k<<<N_NODESC, 320, 0, stream>>>(hraw2, a1s, a1d, es, edv);
    alpha_k <<<(2 * E_TOT + 255) / 256, 256, 0, stream>>>(colsrc, dstof, es, edv, alpha);
    nodems_k<<<(2 * N_NODESC * HEADS + 255) / 256, 256, 0, stream>>>(rowp, alpha, minv);
    agg_slice_k<1><<<12500, 256, 0, stream>>>(rowp, colsrc, alpha, minv, hraw2, b1, h1x2);

    gemm256<0,0><<<RT_TILES * 5, 512, 0, stream>>>(h1x2, F1, w2t, F1,
        hraw2, F1, 20, 5, N_NODESC, nullptr, nullptr);
    escores2_k<<<N_NODESC, 320, 0, stream>>>(hraw2, a2s, a2d, es, edv);
    alpha_k <<<(2 * E_TOT + 255) / 256, 256, 0, stream>>>(colsrc, dstof, es, edv, alpha);
    nodems_k<<<(2 * N_NODESC * HEADS + 255) / 256, 256, 0, stream>>>(rowp, alpha, minv);
    agg_slice_k<0><<<12500, 256, 0, stream>>>(rowp, colsrc, alpha, minv, hraw2, nullptr, tmp2);
    headmean_k<<<1250, 256, 0, stream>>>(tmp2, b2, gx01);

    projsum_k<<<7620, 256, 0, stream>>>(gx01, gx2, Wf, bfv, Wc, bc, out, gsum);
    loss_k  <<<1, 128, 0, stream>>>(gsum, out + 1920000);
}